// Round 1
// baseline (633.388 us; speedup 1.0000x reference)
//
#include <hip/hip_runtime.h>

// ---------------------------------------------------------------------------
// PWAM fused pipeline, bf16 MFMA GEMMs (m97-style 128x128 tile, global_load_lds)
// B=16, HW=3600, D=KC=VC=512, LC=768, NL=20, H=8
// ---------------------------------------------------------------------------

#define B_   16
#define HW_  3600
#define D_   512
#define LC_  768
#define NL_  20

typedef __attribute__((ext_vector_type(8))) __bf16 bf16x8;
typedef __attribute__((ext_vector_type(4))) float f32x4;
typedef __attribute__((ext_vector_type(4))) float float4v;
typedef __attribute__((ext_vector_type(8))) unsigned short ushort8v;
typedef __attribute__((ext_vector_type(4))) unsigned short ushort4v;

static __device__ __forceinline__ float bf2f(unsigned short u){
  unsigned int x = ((unsigned int)u) << 16; float f;
  __builtin_memcpy(&f, &x, 4); return f;
}
static __device__ __forceinline__ unsigned short f2bf(float f){
  unsigned int x; __builtin_memcpy(&x, &f, 4);
  x += 0x7fffu + ((x >> 16) & 1u);
  return (unsigned short)(x >> 16);
}
static __device__ __forceinline__ float gelu_f(float x){
  return 0.5f * x * (1.0f + erff(x * 0.7071067811865476f));
}

// --------------------------- f32 -> bf16 convert ---------------------------
__global__ void k_cvt(const float* __restrict__ src, unsigned short* __restrict__ dst, int n4){
  int i = blockIdx.x * 256 + threadIdx.x;
  int stride = gridDim.x * 256;
  for (; i < n4; i += stride){
    float4v v = ((const float4v*)src)[i];
    ushort4v u;
    u.x = f2bf(v.x); u.y = f2bf(v.y); u.z = f2bf(v.z); u.w = f2bf(v.w);
    ((ushort4v*)dst)[i] = u;
  }
}

// --------------------------- K/V projections (tiny) -------------------------
// k_s[b][c][n] = (Wk[c,:]·l[b,:,n] + bk[c]) * mask[b][n] * 1/sqrt(512)
// v_s[b][c][n] = (Wval[c,:]·l[b,:,n] + bval[c]) * mask[b][n]
__global__ void k_kv(const float* __restrict__ l, const float* __restrict__ l_mask,
                     const float* __restrict__ Wk, const float* __restrict__ bk,
                     const float* __restrict__ Wval, const float* __restrict__ bval,
                     float* __restrict__ k_s, float* __restrict__ v_s){
  const int b = blockIdx.y;
  const int part = blockIdx.x;         // 0..7 -> k chunks, 8..15 -> v chunks
  const bool isK = part < 8;
  const int c0 = (part & 7) * 64;
  const float* W  = isK ? Wk : Wval;
  const float* bi = isK ? bk : bval;
  float* outp = isK ? k_s : v_s;

  __shared__ float l_sh[LC_ * NL_];    // 61440 B
  for (int i = threadIdx.x; i < LC_ * NL_; i += 256)
    l_sh[i] = l[(size_t)b * LC_ * NL_ + i];
  __syncthreads();

  const int tid = threadIdx.x;
  const int cl = tid >> 2;             // 0..63
  const int q  = tid & 3;              // n-quarter: 5 outputs
  const int c  = c0 + cl;
  const float* wrow = W + (size_t)c * LC_;
  float acc[5] = {0.f,0.f,0.f,0.f,0.f};
  for (int i = 0; i < LC_; ++i){
    float wv = wrow[i];
    const float* lr = l_sh + i * NL_ + q * 5;
    acc[0] = fmaf(wv, lr[0], acc[0]);
    acc[1] = fmaf(wv, lr[1], acc[1]);
    acc[2] = fmaf(wv, lr[2], acc[2]);
    acc[3] = fmaf(wv, lr[3], acc[3]);
    acc[4] = fmaf(wv, lr[4], acc[4]);
  }
  const float bb = bi[c];
  #pragma unroll
  for (int n5 = 0; n5 < 5; ++n5){
    int n = q * 5 + n5;
    float m = l_mask[b * NL_ + n];
    float val = (acc[n5] + bb) * m;
    if (isK) val *= 0.04419417382415922f;   // 1/sqrt(512) folded into K
    outp[((size_t)b * 512 + c) * NL_ + n] = val;
  }
}

// --------------------------- GEMM (bf16 MFMA, 128x128 tile) -----------------
// C[m,n] = sum_k A[m,k] * Bm[n,k]   (both K-contiguous), K=512 fixed.
// MODE 0: dual out (N=1024): n<512 -> o0 = bf16(gelu(c+bias0)); else o1 = bf16(c+bias1)
// MODE 1: o0 = bf16(c + bias0)
// MODE 2: of = gelu(c + bias0)   (f32)
template<int MODE>
__global__ __launch_bounds__(256, 2) void k_gemm(
    const unsigned short* __restrict__ A,   // [B][3600][512] bf16
    const unsigned short* __restrict__ Bm,  // [N][512] bf16
    const float* __restrict__ bias0, const float* __restrict__ bias1,
    unsigned short* __restrict__ o0, unsigned short* __restrict__ o1,
    float* __restrict__ of)
{
  __shared__ __align__(16) unsigned short sA[2][128 * 32];
  __shared__ __align__(16) unsigned short sB[2][128 * 32];
  const int b  = blockIdx.z;
  const int m0 = blockIdx.y * 128;
  const int n0 = blockIdx.x * 128;
  const int tid = threadIdx.x;
  const int w = tid >> 6, lane = tid & 63;
  const int wr = w >> 1, wc = w & 1;
  const int mvalid = HW_ - m0;                     // >= 16
  const unsigned short* Ab = A + (size_t)b * HW_ * 512;

  f32x4 acc[4][4];
  #pragma unroll
  for (int i = 0; i < 4; ++i)
    #pragma unroll
    for (int j = 0; j < 4; ++j)
      acc[i][j] = (f32x4){0.f, 0.f, 0.f, 0.f};

  auto stage = [&](int kt, int buf){
    const int k0 = kt * 32;
    #pragma unroll
    for (int s = 0; s < 2; ++s){
      int chunk = s * 256 + tid;
      int row = chunk >> 2, part = chunk & 3;
      int grow = row < mvalid ? row : (mvalid - 1);
      const unsigned short* gsrc = Ab + ((size_t)(m0 + grow) * 512 + k0 + part * 8);
      unsigned short* ldst = &sA[buf][(s * 256 + w * 64) * 8];
      __builtin_amdgcn_global_load_lds((const __attribute__((address_space(1))) void*)gsrc,
                                       (__attribute__((address_space(3))) void*)ldst, 16, 0, 0);
    }
    #pragma unroll
    for (int s = 0; s < 2; ++s){
      int chunk = s * 256 + tid;
      int row = chunk >> 2, part = chunk & 3;
      const unsigned short* gsrc = Bm + ((size_t)(n0 + row) * 512 + k0 + part * 8);
      unsigned short* ldst = &sB[buf][(s * 256 + w * 64) * 8];
      __builtin_amdgcn_global_load_lds((const __attribute__((address_space(1))) void*)gsrc,
                                       (__attribute__((address_space(3))) void*)ldst, 16, 0, 0);
    }
  };

  auto compute = [&](int buf){
    const unsigned short* lA = &sA[buf][(wr * 64) * 32];
    const unsigned short* lB = &sB[buf][(wc * 64) * 32];
    const int r = lane & 15, kb = lane >> 4;
    bf16x8 av[4], bv[4];
    #pragma unroll
    for (int i = 0; i < 4; ++i) av[i] = *(const bf16x8*)(lA + (i * 16 + r) * 32 + kb * 8);
    #pragma unroll
    for (int j = 0; j < 4; ++j) bv[j] = *(const bf16x8*)(lB + (j * 16 + r) * 32 + kb * 8);
    #pragma unroll
    for (int i = 0; i < 4; ++i)
      #pragma unroll
      for (int j = 0; j < 4; ++j)
        acc[i][j] = __builtin_amdgcn_mfma_f32_16x16x32_bf16(av[i], bv[j], acc[i][j], 0, 0, 0);
  };

  stage(0, 0);
  for (int t = 0; t < 16; ++t){
    __syncthreads();
    if (t < 15) stage(t + 1, (t + 1) & 1);
    compute(t & 1);
  }

  // epilogue
  int cols[4]; float bsv[4];
  #pragma unroll
  for (int j = 0; j < 4; ++j){
    int col = n0 + wc * 64 + j * 16 + (lane & 15);
    cols[j] = col;
    if (MODE == 0) bsv[j] = (col < 512) ? bias0[col] : bias1[col - 512];
    else           bsv[j] = bias0[col];
  }
  #pragma unroll
  for (int i = 0; i < 4; ++i){
    int rowb = m0 + wr * 64 + i * 16 + (lane >> 4) * 4;
    #pragma unroll
    for (int rr = 0; rr < 4; ++rr){
      int row = rowb + rr;
      if (row < HW_){
        size_t rb = ((size_t)b * HW_ + row) * 512;
        #pragma unroll
        for (int j = 0; j < 4; ++j){
          float v = acc[i][j][rr] + bsv[j];
          if (MODE == 0){
            if (cols[j] < 512) o0[rb + cols[j]]       = f2bf(gelu_f(v));
            else               o1[rb + cols[j] - 512] = f2bf(v);
          } else if (MODE == 1){
            o0[rb + cols[j]] = f2bf(v);
          } else {
            of[rb + cols[j]] = gelu_f(v);
          }
        }
      }
    }
  }
}

// --------------------------- IN stats (two-stage, deterministic) ------------
__global__ void k_stats_p1(const unsigned short* __restrict__ src, float2* __restrict__ partial){
  const int b = blockIdx.y, chunk = blockIdx.x;   // 16 chunks x 225 rows
  const int tid = threadIdx.x;                    // 128
  const int c0 = tid * 4;
  float s0=0,s1=0,s2=0,s3=0, q0=0,q1=0,q2=0,q3=0;
  const unsigned short* base = src + ((size_t)b * HW_ + chunk * 225) * 512 + c0;
  for (int r = 0; r < 225; ++r){
    ushort4v u = *(const ushort4v*)(base + (size_t)r * 512);
    float f0 = bf2f(u.x), f1 = bf2f(u.y), f2v = bf2f(u.z), f3 = bf2f(u.w);
    s0 += f0; q0 = fmaf(f0, f0, q0);
    s1 += f1; q1 = fmaf(f1, f1, q1);
    s2 += f2v; q2 = fmaf(f2v, f2v, q2);
    s3 += f3; q3 = fmaf(f3, f3, q3);
  }
  size_t pb = ((size_t)b * 16 + chunk) * 512 + c0;
  partial[pb + 0] = make_float2(s0, q0);
  partial[pb + 1] = make_float2(s1, q1);
  partial[pb + 2] = make_float2(s2, q2);
  partial[pb + 3] = make_float2(s3, q3);
}

__global__ void k_stats_p2(const float2* __restrict__ partial, float2* __restrict__ stats){
  const int b = blockIdx.x;
  const int c = threadIdx.x;                       // 512
  float s = 0.f, q = 0.f;
  for (int ch = 0; ch < 16; ++ch){
    float2 p = partial[((size_t)b * 16 + ch) * 512 + c];
    s += p.x; q += p.y;
  }
  float mean = s * (1.0f / (float)HW_);
  float var  = q * (1.0f / (float)HW_) - mean * mean;
  stats[(size_t)b * 512 + c] = make_float2(mean, rsqrtf(var + 1e-5f));
}

// --------------------------- attention (wave-per-row, NL=20) ----------------
// in-place: reads qraw rows (pre-IN, bf16), writes attention output rows.
__global__ __launch_bounds__(256) void k_attn(unsigned short* __restrict__ qraw,
    const float* __restrict__ k_s, const float* __restrict__ v_s,
    const float* __restrict__ l_mask, const float2* __restrict__ stats)
{
  const int b = blockIdx.y, blk = blockIdx.x;     // 30 blocks x 120 rows
  __shared__ __align__(16) unsigned short k_sh[NL_ * 512];
  __shared__ __align__(16) unsigned short v_sh[NL_ * 512];
  __shared__ float bias_sh[NL_];

  for (int i = threadIdx.x; i < 512 * NL_; i += 256){
    int c = i / NL_, n = i % NL_;
    k_sh[n * 512 + c] = f2bf(k_s[(size_t)b * 512 * NL_ + i]);
    v_sh[n * 512 + c] = f2bf(v_s[(size_t)b * 512 * NL_ + i]);
  }
  if (threadIdx.x < NL_)
    bias_sh[threadIdx.x] = 10000.0f * (l_mask[b * NL_ + threadIdx.x] - 1.0f);
  __syncthreads();

  const int w = threadIdx.x >> 6, lane = threadIdx.x & 63;
  const int c0 = lane * 8;
  float mean[8], inv[8];
  #pragma unroll
  for (int j = 0; j < 8; ++j){
    float2 st = stats[(size_t)b * 512 + c0 + j];
    mean[j] = st.x; inv[j] = st.y;
  }

  for (int it = 0; it < 30; ++it){
    int row = blk * 120 + it * 4 + w;
    unsigned short* qp = qraw + ((size_t)b * HW_ + row) * 512 + c0;
    ushort8v qv = *(const ushort8v*)qp;
    float qn[8];
    #pragma unroll
    for (int j = 0; j < 8; ++j) qn[j] = (bf2f(qv[j]) - mean[j]) * inv[j];

    float lg[NL_];
    #pragma unroll
    for (int n = 0; n < NL_; ++n){
      ushort8v kk = *(const ushort8v*)(k_sh + n * 512 + c0);
      float s = 0.f;
      #pragma unroll
      for (int j = 0; j < 8; ++j) s = fmaf(qn[j], bf2f(kk[j]), s);
      lg[n] = s;
    }
    #pragma unroll
    for (int n = 0; n < NL_; ++n){
      lg[n] += __shfl_xor(lg[n], 1);
      lg[n] += __shfl_xor(lg[n], 2);
      lg[n] += __shfl_xor(lg[n], 4);
      lg[n] += bias_sh[n];
    }
    float mx = lg[0];
    #pragma unroll
    for (int n = 1; n < NL_; ++n) mx = fmaxf(mx, lg[n]);
    float sum = 0.f;
    #pragma unroll
    for (int n = 0; n < NL_; ++n){ lg[n] = __expf(lg[n] - mx); sum += lg[n]; }
    float isv = 1.0f / sum;

    float o[8] = {0,0,0,0,0,0,0,0};
    #pragma unroll
    for (int n = 0; n < NL_; ++n){
      float wn = lg[n] * isv;
      ushort8v vv = *(const ushort8v*)(v_sh + n * 512 + c0);
      #pragma unroll
      for (int j = 0; j < 8; ++j) o[j] = fmaf(wn, bf2f(vv[j]), o[j]);
    }
    ushort8v ov;
    #pragma unroll
    for (int j = 0; j < 8; ++j) ov[j] = f2bf(o[j]);
    *(ushort8v*)qp = ov;
  }
}

// --------------------------- h = vis * IN(yw) (in-place over yw) ------------
__global__ __launch_bounds__(256) void k_hmul(unsigned short* __restrict__ yw,
    const unsigned short* __restrict__ visb, const float2* __restrict__ stats)
{
  const int b = blockIdx.y, blk = blockIdx.x;     // 30 blocks x 120 rows
  const int w = threadIdx.x >> 6, lane = threadIdx.x & 63;
  const int c0 = lane * 8;
  float mean[8], inv[8];
  #pragma unroll
  for (int j = 0; j < 8; ++j){
    float2 st = stats[(size_t)b * 512 + c0 + j];
    mean[j] = st.x; inv[j] = st.y;
  }
  for (int it = 0; it < 30; ++it){
    int row = blk * 120 + it * 4 + w;
    size_t off = ((size_t)b * HW_ + row) * 512 + c0;
    ushort8v yv = *(const ushort8v*)(yw + off);
    ushort8v vv = *(const ushort8v*)(visb + off);
    ushort8v hv;
    #pragma unroll
    for (int j = 0; j < 8; ++j){
      float lang = (bf2f(yv[j]) - mean[j]) * inv[j];
      hv[j] = f2bf(bf2f(vv[j]) * lang);
    }
    *(ushort8v*)(yw + off) = hv;
  }
}

// ---------------------------------------------------------------------------
extern "C" void kernel_launch(void* const* d_in, const int* in_sizes, int n_in,
                              void* d_out, int out_size, void* d_ws, size_t ws_size,
                              hipStream_t stream)
{
  const float* x     = (const float*)d_in[0];
  const float* l     = (const float*)d_in[1];
  const float* lmask = (const float*)d_in[2];
  const float* Wvis  = (const float*)d_in[3];
  const float* bvis  = (const float*)d_in[4];
  const float* Wq    = (const float*)d_in[5];
  const float* bq    = (const float*)d_in[6];
  const float* Wk    = (const float*)d_in[7];
  const float* bk    = (const float*)d_in[8];
  const float* Wval  = (const float*)d_in[9];
  const float* bval  = (const float*)d_in[10];
  const float* Ww    = (const float*)d_in[11];
  const float* bw    = (const float*)d_in[12];
  const float* Wmm   = (const float*)d_in[13];
  const float* bmm   = (const float*)d_in[14];
  float* out = (float*)d_out;

  // workspace layout (bytes, all 256-aligned); total = 240,517,120 B
  char* ws = (char*)d_ws;
  if (ws_size < 240517120ull) return;
  unsigned short* xb    = (unsigned short*)(ws + 0);
  unsigned short* visb  = (unsigned short*)(ws + 58982400);
  unsigned short* qraw  = (unsigned short*)(ws + 117964800);
  unsigned short* yw    = (unsigned short*)(ws + 176947200);
  unsigned short* wcat  = (unsigned short*)(ws + 235929600);   // [1024][512] (Wvis|Wq)
  unsigned short* wwb   = (unsigned short*)(ws + 236978176);
  unsigned short* wmmb  = (unsigned short*)(ws + 237502464);
  float*  k_s    = (float*)(ws + 238026752);
  float*  v_s    = (float*)(ws + 238682112);
  float2* partial= (float2*)(ws + 239337472);
  float2* stats_q= (float2*)(ws + 240386048);
  float2* stats_w= (float2*)(ws + 240451584);

  // 1) bf16 conversions
  k_cvt<<<2048, 256, 0, stream>>>(x, xb, (B_ * HW_ * D_) / 4);
  k_cvt<<<256, 256, 0, stream>>>(Wvis, wcat, (512 * 512) / 4);
  k_cvt<<<256, 256, 0, stream>>>(Wq, wcat + 262144, (512 * 512) / 4);
  k_cvt<<<256, 256, 0, stream>>>(Ww, wwb, (512 * 512) / 4);
  k_cvt<<<256, 256, 0, stream>>>(Wmm, wmmb, (512 * 512) / 4);

  // 2) K/V projections (mask + bias + 1/sqrt(KC) folded)
  k_kv<<<dim3(16, B_), 256, 0, stream>>>(l, lmask, Wk, bk, Wval, bval, k_s, v_s);

  // 3) dual GEMM: vis = gelu(x@Wvis^T+bvis), qraw = x@Wq^T+bq
  k_gemm<0><<<dim3(8, 29, B_), 256, 0, stream>>>(xb, wcat, bvis, bq, visb, qraw, nullptr);

  // 4) IN stats for q
  k_stats_p1<<<dim3(16, B_), 128, 0, stream>>>(qraw, partial);
  k_stats_p2<<<B_, 512, 0, stream>>>(partial, stats_q);

  // 5) attention (normalizes q on the fly, in-place output)
  k_attn<<<dim3(30, B_), 256, 0, stream>>>(qraw, k_s, v_s, lmask, stats_q);

  // 6) yw = attn_out @ Ww^T + bw
  k_gemm<1><<<dim3(4, 29, B_), 256, 0, stream>>>(qraw, wwb, bw, nullptr, yw, nullptr, nullptr);

  // 7) IN stats for yw
  k_stats_p1<<<dim3(16, B_), 128, 0, stream>>>(yw, partial);
  k_stats_p2<<<B_, 512, 0, stream>>>(partial, stats_w);

  // 8) h = vis * IN(yw)   (in-place over yw)
  k_hmul<<<dim3(30, B_), 256, 0, stream>>>(yw, visb, stats_w);

  // 9) out = gelu(h @ Wmm^T + bmm)  (f32)
  k_gemm<2><<<dim3(4, 29, B_), 256, 0, stream>>>(yw, wmmb, bmm, nullptr, nullptr, nullptr, out);
}

// Round 2
// 505.032 us; speedup vs baseline: 1.2542x; 1.2542x over previous
//
#include <hip/hip_runtime.h>

// ---------------------------------------------------------------------------
// PWAM fused pipeline, bf16 MFMA GEMMs + MFMA attention (swapped-QK, IN folded)
// B=16, HW=3600, D=KC=VC=512, LC=768, NL=20, H=8
// ---------------------------------------------------------------------------

#define B_   16
#define HW_  3600
#define D_   512
#define LC_  768
#define NL_  20

typedef __attribute__((ext_vector_type(8))) __bf16 bf16x8;
typedef __attribute__((ext_vector_type(4))) float f32x4;
typedef __attribute__((ext_vector_type(4))) float float4v;
typedef __attribute__((ext_vector_type(8))) unsigned short ushort8v;
typedef __attribute__((ext_vector_type(4))) unsigned short ushort4v;
typedef __attribute__((ext_vector_type(2))) unsigned int uint2v;

static __device__ __forceinline__ float bf2f(unsigned short u){
  unsigned int x = ((unsigned int)u) << 16; float f;
  __builtin_memcpy(&f, &x, 4); return f;
}
static __device__ __forceinline__ unsigned short f2bf(float f){
  unsigned int x; __builtin_memcpy(&x, &f, 4);
  x += 0x7fffu + ((x >> 16) & 1u);
  return (unsigned short)(x >> 16);
}
static __device__ __forceinline__ unsigned int pack2bf(float lo, float hi){
  return (unsigned int)f2bf(lo) | ((unsigned int)f2bf(hi) << 16);
}
static __device__ __forceinline__ float gelu_f(float x){
  return 0.5f * x * (1.0f + erff(x * 0.7071067811865476f));
}

// --------------------------- f32 -> bf16 convert ---------------------------
__global__ void k_cvt(const float* __restrict__ src, unsigned short* __restrict__ dst, int n4){
  int i = blockIdx.x * 256 + threadIdx.x;
  int stride = gridDim.x * 256;
  for (; i < n4; i += stride){
    float4v v = ((const float4v*)src)[i];
    ushort4v u;
    u.x = f2bf(v.x); u.y = f2bf(v.y); u.z = f2bf(v.z); u.w = f2bf(v.w);
    ((ushort4v*)dst)[i] = u;
  }
}

// --------------------------- K/V projections (tiny) -------------------------
__global__ void k_kv(const float* __restrict__ l, const float* __restrict__ l_mask,
                     const float* __restrict__ Wk, const float* __restrict__ bk,
                     const float* __restrict__ Wval, const float* __restrict__ bval,
                     float* __restrict__ k_s, float* __restrict__ v_s){
  const int b = blockIdx.y;
  const int part = blockIdx.x;         // 0..7 -> k chunks, 8..15 -> v chunks
  const bool isK = part < 8;
  const int c0 = (part & 7) * 64;
  const float* W  = isK ? Wk : Wval;
  const float* bi = isK ? bk : bval;
  float* outp = isK ? k_s : v_s;

  __shared__ float l_sh[LC_ * NL_];
  for (int i = threadIdx.x; i < LC_ * NL_; i += 256)
    l_sh[i] = l[(size_t)b * LC_ * NL_ + i];
  __syncthreads();

  const int tid = threadIdx.x;
  const int cl = tid >> 2;
  const int q  = tid & 3;
  const int c  = c0 + cl;
  const float* wrow = W + (size_t)c * LC_;
  float acc[5] = {0.f,0.f,0.f,0.f,0.f};
  for (int i = 0; i < LC_; ++i){
    float wv = wrow[i];
    const float* lr = l_sh + i * NL_ + q * 5;
    acc[0] = fmaf(wv, lr[0], acc[0]);
    acc[1] = fmaf(wv, lr[1], acc[1]);
    acc[2] = fmaf(wv, lr[2], acc[2]);
    acc[3] = fmaf(wv, lr[3], acc[3]);
    acc[4] = fmaf(wv, lr[4], acc[4]);
  }
  const float bb = bi[c];
  #pragma unroll
  for (int n5 = 0; n5 < 5; ++n5){
    int n = q * 5 + n5;
    float m = l_mask[b * NL_ + n];
    float val = (acc[n5] + bb) * m;
    if (isK) val *= 0.04419417382415922f;   // 1/sqrt(512) folded into K
    outp[((size_t)b * 512 + c) * NL_ + n] = val;
  }
}

// --------------------------- GEMM (bf16 MFMA, 128x128 tile) -----------------
template<int MODE>
__global__ __launch_bounds__(256, 2) void k_gemm(
    const unsigned short* __restrict__ A,
    const unsigned short* __restrict__ Bm,
    const float* __restrict__ bias0, const float* __restrict__ bias1,
    unsigned short* __restrict__ o0, unsigned short* __restrict__ o1,
    float* __restrict__ of)
{
  __shared__ __align__(16) unsigned short sA[2][128 * 32];
  __shared__ __align__(16) unsigned short sB[2][128 * 32];
  const int b  = blockIdx.z;
  const int m0 = blockIdx.y * 128;
  const int n0 = blockIdx.x * 128;
  const int tid = threadIdx.x;
  const int w = tid >> 6, lane = tid & 63;
  const int wr = w >> 1, wc = w & 1;
  const int mvalid = HW_ - m0;
  const unsigned short* Ab = A + (size_t)b * HW_ * 512;

  f32x4 acc[4][4];
  #pragma unroll
  for (int i = 0; i < 4; ++i)
    #pragma unroll
    for (int j = 0; j < 4; ++j)
      acc[i][j] = (f32x4){0.f, 0.f, 0.f, 0.f};

  auto stage = [&](int kt, int buf){
    const int k0 = kt * 32;
    #pragma unroll
    for (int s = 0; s < 2; ++s){
      int chunk = s * 256 + tid;
      int row = chunk >> 2, part = chunk & 3;
      int grow = row < mvalid ? row : (mvalid - 1);
      const unsigned short* gsrc = Ab + ((size_t)(m0 + grow) * 512 + k0 + part * 8);
      unsigned short* ldst = &sA[buf][(s * 256 + w * 64) * 8];
      __builtin_amdgcn_global_load_lds((const __attribute__((address_space(1))) void*)gsrc,
                                       (__attribute__((address_space(3))) void*)ldst, 16, 0, 0);
    }
    #pragma unroll
    for (int s = 0; s < 2; ++s){
      int chunk = s * 256 + tid;
      int row = chunk >> 2, part = chunk & 3;
      const unsigned short* gsrc = Bm + ((size_t)(n0 + row) * 512 + k0 + part * 8);
      unsigned short* ldst = &sB[buf][(s * 256 + w * 64) * 8];
      __builtin_amdgcn_global_load_lds((const __attribute__((address_space(1))) void*)gsrc,
                                       (__attribute__((address_space(3))) void*)ldst, 16, 0, 0);
    }
  };

  auto compute = [&](int buf){
    const unsigned short* lA = &sA[buf][(wr * 64) * 32];
    const unsigned short* lB = &sB[buf][(wc * 64) * 32];
    const int r = lane & 15, kb = lane >> 4;
    bf16x8 av[4], bv[4];
    #pragma unroll
    for (int i = 0; i < 4; ++i) av[i] = *(const bf16x8*)(lA + (i * 16 + r) * 32 + kb * 8);
    #pragma unroll
    for (int j = 0; j < 4; ++j) bv[j] = *(const bf16x8*)(lB + (j * 16 + r) * 32 + kb * 8);
    #pragma unroll
    for (int i = 0; i < 4; ++i)
      #pragma unroll
      for (int j = 0; j < 4; ++j)
        acc[i][j] = __builtin_amdgcn_mfma_f32_16x16x32_bf16(av[i], bv[j], acc[i][j], 0, 0, 0);
  };

  stage(0, 0);
  for (int t = 0; t < 16; ++t){
    __syncthreads();
    if (t < 15) stage(t + 1, (t + 1) & 1);
    compute(t & 1);
  }

  int cols[4]; float bsv[4];
  #pragma unroll
  for (int j = 0; j < 4; ++j){
    int col = n0 + wc * 64 + j * 16 + (lane & 15);
    cols[j] = col;
    if (MODE == 0) bsv[j] = (col < 512) ? bias0[col] : bias1[col - 512];
    else           bsv[j] = bias0[col];
  }
  #pragma unroll
  for (int i = 0; i < 4; ++i){
    int rowb = m0 + wr * 64 + i * 16 + (lane >> 4) * 4;
    #pragma unroll
    for (int rr = 0; rr < 4; ++rr){
      int row = rowb + rr;
      if (row < HW_){
        size_t rb = ((size_t)b * HW_ + row) * 512;
        #pragma unroll
        for (int j = 0; j < 4; ++j){
          float v = acc[i][j][rr] + bsv[j];
          if (MODE == 0){
            if (cols[j] < 512) o0[rb + cols[j]]       = f2bf(gelu_f(v));
            else               o1[rb + cols[j] - 512] = f2bf(v);
          } else if (MODE == 1){
            o0[rb + cols[j]] = f2bf(v);
          } else {
            of[rb + cols[j]] = gelu_f(v);
          }
        }
      }
    }
  }
}

// --------------------------- IN stats (two-stage, deterministic) ------------
__global__ void k_stats_p1(const unsigned short* __restrict__ src, float2* __restrict__ partial){
  const int b = blockIdx.y, chunk = blockIdx.x;
  const int tid = threadIdx.x;
  const int c0 = tid * 4;
  float s0=0,s1=0,s2=0,s3=0, q0=0,q1=0,q2=0,q3=0;
  const unsigned short* base = src + ((size_t)b * HW_ + chunk * 225) * 512 + c0;
  for (int r = 0; r < 225; ++r){
    ushort4v u = *(const ushort4v*)(base + (size_t)r * 512);
    float f0 = bf2f(u.x), f1 = bf2f(u.y), f2v = bf2f(u.z), f3 = bf2f(u.w);
    s0 += f0; q0 = fmaf(f0, f0, q0);
    s1 += f1; q1 = fmaf(f1, f1, q1);
    s2 += f2v; q2 = fmaf(f2v, f2v, q2);
    s3 += f3; q3 = fmaf(f3, f3, q3);
  }
  size_t pb = ((size_t)b * 16 + chunk) * 512 + c0;
  partial[pb + 0] = make_float2(s0, q0);
  partial[pb + 1] = make_float2(s1, q1);
  partial[pb + 2] = make_float2(s2, q2);
  partial[pb + 3] = make_float2(s3, q3);
}

__global__ void k_stats_p2(const float2* __restrict__ partial, float2* __restrict__ stats){
  const int b = blockIdx.x;
  const int c = threadIdx.x;
  float s = 0.f, q = 0.f;
  for (int ch = 0; ch < 16; ++ch){
    float2 p = partial[((size_t)b * 16 + ch) * 512 + c];
    s += p.x; q += p.y;
  }
  float mean = s * (1.0f / (float)HW_);
  float var  = q * (1.0f / (float)HW_) - mean * mean;
  stats[(size_t)b * 512 + c] = make_float2(mean, rsqrtf(var + 1e-5f));
}

// --------------------------- attention prep ---------------------------------
// Builds, per batch b:
//  k2[b][h][t][s][lane][j] bf16 : K' A-fragments, K'[n][c] = inv[c]*k_s[b][c][n], 0 for n>=20
//  v2[b][h][ct][lane][j]   bf16 : V  A-fragments, V[n][c]  = v_s[b][c][n],        0 for n>=20
//  e_s[b][n] (n<32) f32 : -d_n - 10000*(1-mask) for n<20 (d_n = sum_c mean*inv*k_s), else -1e30
__global__ void k_prep(const float* __restrict__ k_s, const float* __restrict__ v_s,
                       const float2* __restrict__ stats, const float* __restrict__ l_mask,
                       unsigned short* __restrict__ k2, unsigned short* __restrict__ v2,
                       float* __restrict__ e_s)
{
  const int b = blockIdx.x;
  const int tid = threadIdx.x;
  __shared__ float wred[4][NL_];

  // ---- d_n reduction: each thread covers c = tid and c = tid+256 ----
  float part[NL_];
  #pragma unroll
  for (int n = 0; n < NL_; ++n) part[n] = 0.f;
  #pragma unroll
  for (int half = 0; half < 2; ++half){
    int c = tid + half * 256;
    float2 st = stats[(size_t)b * 512 + c];
    float ms = st.x * st.y;
    const float* row = k_s + ((size_t)b * 512 + c) * NL_;
    #pragma unroll
    for (int n = 0; n < NL_; ++n) part[n] = fmaf(ms, row[n], part[n]);
  }
  #pragma unroll
  for (int n = 0; n < NL_; ++n){
    float v = part[n];
    v += __shfl_xor(v, 1);  v += __shfl_xor(v, 2);  v += __shfl_xor(v, 4);
    v += __shfl_xor(v, 8);  v += __shfl_xor(v, 16); v += __shfl_xor(v, 32);
    part[n] = v;
  }
  if ((tid & 63) == 0){
    #pragma unroll
    for (int n = 0; n < NL_; ++n) wred[tid >> 6][n] = part[n];
  }
  __syncthreads();
  if (tid < 32){
    float e;
    if (tid < NL_){
      float d = wred[0][tid] + wred[1][tid] + wred[2][tid] + wred[3][tid];
      e = -d - 10000.0f * (1.0f - l_mask[b * NL_ + tid]);
    } else {
      e = -1e30f;
    }
    e_s[b * 32 + tid] = e;
  }

  // ---- K' fragments ----
  for (int i = tid; i < 16384; i += 256){
    int h = i >> 11, t = (i >> 10) & 1, s = (i >> 9) & 1;
    int l = (i >> 3) & 63, j = i & 7;
    int r = l & 15, g = l >> 4;
    int n = t * 16 + r;
    int c = h * 64 + s * 32 + g * 8 + j;
    unsigned short val = 0;
    if (n < NL_){
      float inv = stats[(size_t)b * 512 + c].y;
      val = f2bf(inv * k_s[((size_t)b * 512 + c) * NL_ + n]);
    }
    k2[(size_t)b * 16384 + i] = val;
  }
  // ---- V fragments ----
  for (int i = tid; i < 16384; i += 256){
    int h = i >> 11, ct = (i >> 9) & 3;
    int l = (i >> 3) & 63, j = i & 7;
    int r = l & 15, g = l >> 4;
    int n = g * 8 + j;
    int c = h * 64 + ct * 16 + r;
    unsigned short val = 0;
    if (n < NL_) val = f2bf(v_s[((size_t)b * 512 + c) * NL_ + n]);
    v2[(size_t)b * 16384 + i] = val;
  }
}

// --------------------------- attention (MFMA, swapped-QK) -------------------
// Per wave: 16 Q-rows x 8 heads. Q raw bf16 from global (IN folded into K'/e).
// In-place output over qraw. No cross-wave data -> no barriers.
__global__ __launch_bounds__(256) void k_attn2(unsigned short* __restrict__ qraw,
    const unsigned short* __restrict__ k2, const unsigned short* __restrict__ v2,
    const float* __restrict__ e_s)
{
  const int b = blockIdx.y;
  const int w = threadIdx.x >> 6;
  const int tile = blockIdx.x * 4 + w;
  __shared__ __align__(16) unsigned short p_sh[4][16 * 32];   // [q][n] per wave
  __shared__ __align__(16) unsigned short o_sh[4][16 * 72];   // [q][64c pad 72] per wave
  if (tile >= 225) return;
  const int lane = threadIdx.x & 63;
  const int r = lane & 15, g = lane >> 4;
  const int row0 = tile * 16;

  float4v e0 = *(const float4v*)(e_s + b * 32 + g * 4);        // n = 4g+reg
  float4v e1 = *(const float4v*)(e_s + b * 32 + 16 + g * 4);   // n = 16+4g+reg

  // preload all Q B-fragments (col=q=r, k=c-chunk) — enables in-place writes
  bf16x8 qf[8][2];
  const unsigned short* qbase = qraw + ((size_t)(b * HW_ + row0 + r) * 512) + g * 8;
  #pragma unroll
  for (int h = 0; h < 8; ++h)
    #pragma unroll
    for (int s = 0; s < 2; ++s)
      qf[h][s] = *(const bf16x8*)(qbase + h * 64 + s * 32);

  const unsigned short* kb = k2 + (size_t)b * 16384 + lane * 8;
  const unsigned short* vb = v2 + (size_t)b * 16384 + lane * 8;
  unsigned short* psh = &p_sh[w][0];
  unsigned short* osh = &o_sh[w][0];

  for (int h = 0; h < 8; ++h){
    // ---- QK^T (swapped): C[n, q] ----
    bf16x8 kf00 = *(const bf16x8*)(kb + (h * 4 + 0) * 512);
    bf16x8 kf01 = *(const bf16x8*)(kb + (h * 4 + 1) * 512);
    bf16x8 kf10 = *(const bf16x8*)(kb + (h * 4 + 2) * 512);
    bf16x8 kf11 = *(const bf16x8*)(kb + (h * 4 + 3) * 512);
    f32x4 c0 = (f32x4){0.f,0.f,0.f,0.f};
    f32x4 c1 = (f32x4){0.f,0.f,0.f,0.f};
    c0 = __builtin_amdgcn_mfma_f32_16x16x32_bf16(kf00, qf[h][0], c0, 0, 0, 0);
    c0 = __builtin_amdgcn_mfma_f32_16x16x32_bf16(kf01, qf[h][1], c0, 0, 0, 0);
    c1 = __builtin_amdgcn_mfma_f32_16x16x32_bf16(kf10, qf[h][0], c1, 0, 0, 0);
    c1 = __builtin_amdgcn_mfma_f32_16x16x32_bf16(kf11, qf[h][1], c1, 0, 0, 0);

    // ---- softmax over n (lane-local 8 + cross-group shfl) ----
    float l0[4], l1[4];
    #pragma unroll
    for (int i = 0; i < 4; ++i){ l0[i] = c0[i] + e0[i]; l1[i] = c1[i] + e1[i]; }
    float m = fmaxf(fmaxf(fmaxf(l0[0], l0[1]), fmaxf(l0[2], l0[3])),
                    fmaxf(fmaxf(l1[0], l1[1]), fmaxf(l1[2], l1[3])));
    m = fmaxf(m, __shfl_xor(m, 16));
    m = fmaxf(m, __shfl_xor(m, 32));
    float p0[4], p1[4], sum = 0.f;
    #pragma unroll
    for (int i = 0; i < 4; ++i){ p0[i] = __expf(l0[i] - m); sum += p0[i]; }
    #pragma unroll
    for (int i = 0; i < 4; ++i){ p1[i] = __expf(l1[i] - m); sum += p1[i]; }
    sum += __shfl_xor(sum, 16);
    sum += __shfl_xor(sum, 32);
    float inv = 1.0f / sum;
    #pragma unroll
    for (int i = 0; i < 4; ++i){ p0[i] *= inv; p1[i] *= inv; }

    // ---- P -> bf16 into wave-private LDS [q][n] ----
    uint2v pw0, pw1;
    pw0.x = pack2bf(p0[0], p0[1]); pw0.y = pack2bf(p0[2], p0[3]);
    pw1.x = pack2bf(p1[0], p1[1]); pw1.y = pack2bf(p1[2], p1[3]);
    *(uint2v*)(psh + r * 32 + 4 * g)      = pw0;   // n = 4g..4g+3
    *(uint2v*)(psh + r * 32 + 16 + 4 * g) = pw1;   // n = 16+4g..
    // B-fragment read: col=q=r, k = n = g*8..g*8+7
    bf16x8 pfrag = *(const bf16x8*)(psh + r * 32 + g * 8);

    // ---- PV (out^T): D[c-sub, q] per 16-c tile ----
    f32x4 dd[4];
    #pragma unroll
    for (int ct = 0; ct < 4; ++ct){
      bf16x8 vf = *(const bf16x8*)(vb + (h * 4 + ct) * 512);
      f32x4 z = (f32x4){0.f,0.f,0.f,0.f};
      dd[ct] = __builtin_amdgcn_mfma_f32_16x16x32_bf16(vf, pfrag, z, 0, 0, 0);
    }
    // stage to LDS: o_sh[q][ct*16 + 4g + reg]
    #pragma unroll
    for (int ct = 0; ct < 4; ++ct){
      uint2v ow;
      ow.x = pack2bf(dd[ct][0], dd[ct][1]);
      ow.y = pack2bf(dd[ct][2], dd[ct][3]);
      *(uint2v*)(osh + r * 72 + ct * 16 + 4 * g) = ow;
    }
    // flush: 16 rows x 64 ch (128B/row), coalesced
    int frow = lane >> 2, fch = lane & 3;
    ushort8v t0 = *(const ushort8v*)(osh + frow * 72 + fch * 16);
    ushort8v t1 = *(const ushort8v*)(osh + frow * 72 + fch * 16 + 8);
    unsigned short* gdst = qraw + ((size_t)(b * HW_ + row0 + frow) * 512) + h * 64 + fch * 16;
    *(ushort8v*)(gdst)     = t0;
    *(ushort8v*)(gdst + 8) = t1;
  }
}

// --------------------------- h = vis * IN(yw) (in-place over yw) ------------
__global__ __launch_bounds__(256) void k_hmul(unsigned short* __restrict__ yw,
    const unsigned short* __restrict__ visb, const float2* __restrict__ stats)
{
  const int b = blockIdx.y, blk = blockIdx.x;
  const int w = threadIdx.x >> 6, lane = threadIdx.x & 63;
  const int c0 = lane * 8;
  float mean[8], inv[8];
  #pragma unroll
  for (int j = 0; j < 8; ++j){
    float2 st = stats[(size_t)b * 512 + c0 + j];
    mean[j] = st.x; inv[j] = st.y;
  }
  for (int it = 0; it < 30; ++it){
    int row = blk * 120 + it * 4 + w;
    size_t off = ((size_t)b * HW_ + row) * 512 + c0;
    ushort8v yv = *(const ushort8v*)(yw + off);
    ushort8v vv = *(const ushort8v*)(visb + off);
    ushort8v hv;
    #pragma unroll
    for (int j = 0; j < 8; ++j){
      float lang = (bf2f(yv[j]) - mean[j]) * inv[j];
      hv[j] = f2bf(bf2f(vv[j]) * lang);
    }
    *(ushort8v*)(yw + off) = hv;
  }
}

// ---------------------------------------------------------------------------
extern "C" void kernel_launch(void* const* d_in, const int* in_sizes, int n_in,
                              void* d_out, int out_size, void* d_ws, size_t ws_size,
                              hipStream_t stream)
{
  const float* x     = (const float*)d_in[0];
  const float* l     = (const float*)d_in[1];
  const float* lmask = (const float*)d_in[2];
  const float* Wvis  = (const float*)d_in[3];
  const float* bvis  = (const float*)d_in[4];
  const float* Wq    = (const float*)d_in[5];
  const float* bq    = (const float*)d_in[6];
  const float* Wk    = (const float*)d_in[7];
  const float* bk    = (const float*)d_in[8];
  const float* Wval  = (const float*)d_in[9];
  const float* bval  = (const float*)d_in[10];
  const float* Ww    = (const float*)d_in[11];
  const float* bw    = (const float*)d_in[12];
  const float* Wmm   = (const float*)d_in[13];
  const float* bmm   = (const float*)d_in[14];
  float* out = (float*)d_out;

  char* ws = (char*)d_ws;
  if (ws_size < 240517120ull) return;
  unsigned short* xb    = (unsigned short*)(ws + 0);
  unsigned short* visb  = (unsigned short*)(ws + 58982400);
  unsigned short* qraw  = (unsigned short*)(ws + 117964800);
  unsigned short* yw    = (unsigned short*)(ws + 176947200);
  unsigned short* wcat  = (unsigned short*)(ws + 235929600);
  unsigned short* wwb   = (unsigned short*)(ws + 236978176);
  unsigned short* wmmb  = (unsigned short*)(ws + 237502464);
  float*  k_s    = (float*)(ws + 238026752);
  float*  v_s    = (float*)(ws + 238682112);
  float2* partial= (float2*)(ws + 239337472);
  float2* stats_q= (float2*)(ws + 240386048);
  float2* stats_w= (float2*)(ws + 240451584);
  // attention fragment buffers overlap xb (dead after GEMM1):
  unsigned short* k2 = (unsigned short*)(ws + 0);          // 512 KB
  unsigned short* v2 = (unsigned short*)(ws + 524288);     // 512 KB
  float*          e_s = (float*)(ws + 1048576);            // 2 KB

  // 1) bf16 conversions
  k_cvt<<<2048, 256, 0, stream>>>(x, xb, (B_ * HW_ * D_) / 4);
  k_cvt<<<256, 256, 0, stream>>>(Wvis, wcat, (512 * 512) / 4);
  k_cvt<<<256, 256, 0, stream>>>(Wq, wcat + 262144, (512 * 512) / 4);
  k_cvt<<<256, 256, 0, stream>>>(Ww, wwb, (512 * 512) / 4);
  k_cvt<<<256, 256, 0, stream>>>(Wmm, wmmb, (512 * 512) / 4);

  // 2) K/V projections (mask + bias + 1/sqrt(KC) folded)
  k_kv<<<dim3(16, B_), 256, 0, stream>>>(l, lmask, Wk, bk, Wval, bval, k_s, v_s);

  // 3) dual GEMM: vis = gelu(x@Wvis^T+bvis), qraw = x@Wq^T+bq
  k_gemm<0><<<dim3(8, 29, B_), 256, 0, stream>>>(xb, wcat, bvis, bq, visb, qraw, nullptr);

  // 4) IN stats for q
  k_stats_p1<<<dim3(16, B_), 128, 0, stream>>>(qraw, partial);
  k_stats_p2<<<B_, 512, 0, stream>>>(partial, stats_q);

  // 4.5) build MFMA fragments for attention (overwrites dead xb region)
  k_prep<<<B_, 256, 0, stream>>>(k_s, v_s, stats_q, lmask, k2, v2, e_s);

  // 5) MFMA attention, in-place over qraw
  k_attn2<<<dim3(57, B_), 256, 0, stream>>>(qraw, k2, v2, e_s);

  // 6) yw = attn_out @ Ww^T + bw
  k_gemm<1><<<dim3(4, 29, B_), 256, 0, stream>>>(qraw, wwb, bw, nullptr, yw, nullptr, nullptr);

  // 7) IN stats for yw
  k_stats_p1<<<dim3(16, B_), 128, 0, stream>>>(yw, partial);
  k_stats_p2<<<B_, 512, 0, stream>>>(partial, stats_w);

  // 8) h = vis * IN(yw)   (in-place over yw)
  k_hmul<<<dim3(30, B_), 256, 0, stream>>>(yw, visb, stats_w);

  // 9) out = gelu(h @ Wmm^T + bmm)  (f32)
  k_gemm<2><<<dim3(4, 29, B_), 256, 0, stream>>>(yw, wmmb, bmm, nullptr, nullptr, nullptr, out);
}

// Round 3
// 467.539 us; speedup vs baseline: 1.3547x; 1.0802x over previous
//
#include <hip/hip_runtime.h>

// ---------------------------------------------------------------------------
// PWAM fused pipeline, bf16 MFMA GEMMs + MFMA attention (swapped-QK, IN folded)
// R3: XCD-bijective swizzle on GEMM grids, IN-stats fused into GEMM epilogues,
//     softmax normalized post-bf16-rounding.
// B=16, HW=3600, D=KC=VC=512, LC=768, NL=20, H=8
// ---------------------------------------------------------------------------

#define B_   16
#define HW_  3600
#define D_   512
#define LC_  768
#define NL_  20

typedef __attribute__((ext_vector_type(8))) __bf16 bf16x8;
typedef __attribute__((ext_vector_type(4))) float f32x4;
typedef __attribute__((ext_vector_type(4))) float float4v;
typedef __attribute__((ext_vector_type(8))) unsigned short ushort8v;
typedef __attribute__((ext_vector_type(4))) unsigned short ushort4v;
typedef __attribute__((ext_vector_type(2))) unsigned int uint2v;

static __device__ __forceinline__ float bf2f(unsigned short u){
  unsigned int x = ((unsigned int)u) << 16; float f;
  __builtin_memcpy(&f, &x, 4); return f;
}
static __device__ __forceinline__ unsigned short f2bf(float f){
  unsigned int x; __builtin_memcpy(&x, &f, 4);
  x += 0x7fffu + ((x >> 16) & 1u);
  return (unsigned short)(x >> 16);
}
static __device__ __forceinline__ unsigned int pack2bf(float lo, float hi){
  return (unsigned int)f2bf(lo) | ((unsigned int)f2bf(hi) << 16);
}
static __device__ __forceinline__ float gelu_f(float x){
  return 0.5f * x * (1.0f + erff(x * 0.7071067811865476f));
}

// --------------------------- f32 -> bf16 convert ---------------------------
__global__ void k_cvt(const float* __restrict__ src, unsigned short* __restrict__ dst, int n4){
  int i = blockIdx.x * 256 + threadIdx.x;
  int stride = gridDim.x * 256;
  for (; i < n4; i += stride){
    float4v v = ((const float4v*)src)[i];
    ushort4v u;
    u.x = f2bf(v.x); u.y = f2bf(v.y); u.z = f2bf(v.z); u.w = f2bf(v.w);
    ((ushort4v*)dst)[i] = u;
  }
}

// --------------------------- K/V projections (tiny) -------------------------
__global__ void k_kv(const float* __restrict__ l, const float* __restrict__ l_mask,
                     const float* __restrict__ Wk, const float* __restrict__ bk,
                     const float* __restrict__ Wval, const float* __restrict__ bval,
                     float* __restrict__ k_s, float* __restrict__ v_s){
  const int b = blockIdx.y;
  const int part = blockIdx.x;
  const bool isK = part < 8;
  const int c0 = (part & 7) * 64;
  const float* W  = isK ? Wk : Wval;
  const float* bi = isK ? bk : bval;
  float* outp = isK ? k_s : v_s;

  __shared__ float l_sh[LC_ * NL_];
  for (int i = threadIdx.x; i < LC_ * NL_; i += 256)
    l_sh[i] = l[(size_t)b * LC_ * NL_ + i];
  __syncthreads();

  const int tid = threadIdx.x;
  const int cl = tid >> 2;
  const int q  = tid & 3;
  const int c  = c0 + cl;
  const float* wrow = W + (size_t)c * LC_;
  float acc[5] = {0.f,0.f,0.f,0.f,0.f};
  for (int i = 0; i < LC_; ++i){
    float wv = wrow[i];
    const float* lr = l_sh + i * NL_ + q * 5;
    acc[0] = fmaf(wv, lr[0], acc[0]);
    acc[1] = fmaf(wv, lr[1], acc[1]);
    acc[2] = fmaf(wv, lr[2], acc[2]);
    acc[3] = fmaf(wv, lr[3], acc[3]);
    acc[4] = fmaf(wv, lr[4], acc[4]);
  }
  const float bb = bi[c];
  #pragma unroll
  for (int n5 = 0; n5 < 5; ++n5){
    int n = q * 5 + n5;
    float m = l_mask[b * NL_ + n];
    float val = (acc[n5] + bb) * m;
    if (isK) val *= 0.04419417382415922f;   // 1/sqrt(512) folded into K
    outp[((size_t)b * 512 + c) * NL_ + n] = val;
  }
}

// --------------------------- GEMM (bf16 MFMA, 128x128 tile) -----------------
// 1-D grid, XCD-bijective swizzle (nwg % 8 == 0), n-tile fastest.
// MODE 0: dual out (NT=8): n<512 -> o0=bf16(gelu(c+bias0)); else o1=bf16(c+bias1)
// MODE 1: o0 = bf16(c + bias0)
// MODE 2: of = gelu(c + bias0)   (f32)
// STATS: per-block column sum/sumsq of the f32 value -> partial[(b*29+mt)*512+col]
template<int MODE, int NT, bool STATS>
__global__ __launch_bounds__(256, 2) void k_gemm(
    const unsigned short* __restrict__ A,
    const unsigned short* __restrict__ Bm,
    const float* __restrict__ bias0, const float* __restrict__ bias1,
    unsigned short* __restrict__ o0, unsigned short* __restrict__ o1,
    float* __restrict__ of, float2* __restrict__ partial)
{
  __shared__ __align__(16) unsigned short sA[2][128 * 32];
  __shared__ __align__(16) unsigned short sB[2][128 * 32];
  __shared__ float2 red[2][128];

  // XCD swizzle: d%8 -> XCD; give each XCD contiguous g-range, n fastest in g.
  const int nwg = 29 * NT * B_;
  const int per = nwg >> 3;
  const int d = blockIdx.x;
  const int g = (d & 7) * per + (d >> 3);
  constexpr int NSH = (NT == 8) ? 3 : 2;
  const int nt = g & (NT - 1);
  const int rem = g >> NSH;
  const int mt = rem % 29;
  const int b  = rem / 29;

  const int m0 = mt * 128;
  const int n0 = nt * 128;
  const int tid = threadIdx.x;
  const int w = tid >> 6, lane = tid & 63;
  const int wr = w >> 1, wc = w & 1;
  const int mvalid = HW_ - m0;
  const unsigned short* Ab = A + (size_t)b * HW_ * 512;

  f32x4 acc[4][4];
  #pragma unroll
  for (int i = 0; i < 4; ++i)
    #pragma unroll
    for (int j = 0; j < 4; ++j)
      acc[i][j] = (f32x4){0.f, 0.f, 0.f, 0.f};

  auto stage = [&](int kt, int buf){
    const int k0 = kt * 32;
    #pragma unroll
    for (int s = 0; s < 2; ++s){
      int chunk = s * 256 + tid;
      int row = chunk >> 2, part = chunk & 3;
      int grow = row < mvalid ? row : (mvalid - 1);
      const unsigned short* gsrc = Ab + ((size_t)(m0 + grow) * 512 + k0 + part * 8);
      unsigned short* ldst = &sA[buf][(s * 256 + w * 64) * 8];
      __builtin_amdgcn_global_load_lds((const __attribute__((address_space(1))) void*)gsrc,
                                       (__attribute__((address_space(3))) void*)ldst, 16, 0, 0);
    }
    #pragma unroll
    for (int s = 0; s < 2; ++s){
      int chunk = s * 256 + tid;
      int row = chunk >> 2, part = chunk & 3;
      const unsigned short* gsrc = Bm + ((size_t)(n0 + row) * 512 + k0 + part * 8);
      unsigned short* ldst = &sB[buf][(s * 256 + w * 64) * 8];
      __builtin_amdgcn_global_load_lds((const __attribute__((address_space(1))) void*)gsrc,
                                       (__attribute__((address_space(3))) void*)ldst, 16, 0, 0);
    }
  };

  auto compute = [&](int buf){
    const unsigned short* lA = &sA[buf][(wr * 64) * 32];
    const unsigned short* lB = &sB[buf][(wc * 64) * 32];
    const int r = lane & 15, kb = lane >> 4;
    bf16x8 av[4], bv[4];
    #pragma unroll
    for (int i = 0; i < 4; ++i) av[i] = *(const bf16x8*)(lA + (i * 16 + r) * 32 + kb * 8);
    #pragma unroll
    for (int j = 0; j < 4; ++j) bv[j] = *(const bf16x8*)(lB + (j * 16 + r) * 32 + kb * 8);
    #pragma unroll
    for (int i = 0; i < 4; ++i)
      #pragma unroll
      for (int j = 0; j < 4; ++j)
        acc[i][j] = __builtin_amdgcn_mfma_f32_16x16x32_bf16(av[i], bv[j], acc[i][j], 0, 0, 0);
  };

  stage(0, 0);
  for (int t = 0; t < 16; ++t){
    __syncthreads();
    if (t < 15) stage(t + 1, (t + 1) & 1);
    compute(t & 1);
  }

  // ---- epilogue ----
  int cols[4]; float bsv[4];
  #pragma unroll
  for (int j = 0; j < 4; ++j){
    int col = n0 + wc * 64 + j * 16 + (lane & 15);
    cols[j] = col;
    if (MODE == 0) bsv[j] = (col < 512) ? bias0[col] : bias1[col - 512];
    else           bsv[j] = bias0[col];
  }
  const bool do_stats = STATS && (MODE != 0 || n0 >= 512);
  float colsum[4] = {0.f,0.f,0.f,0.f}, colsq[4] = {0.f,0.f,0.f,0.f};

  #pragma unroll
  for (int i = 0; i < 4; ++i){
    int rowb = m0 + wr * 64 + i * 16 + (lane >> 4) * 4;
    #pragma unroll
    for (int rr = 0; rr < 4; ++rr){
      int row = rowb + rr;
      if (row < HW_){
        size_t rb = ((size_t)b * HW_ + row) * 512;
        #pragma unroll
        for (int j = 0; j < 4; ++j){
          float v = acc[i][j][rr] + bsv[j];
          if (MODE == 0){
            if (cols[j] < 512) o0[rb + cols[j]]       = f2bf(gelu_f(v));
            else               o1[rb + cols[j] - 512] = f2bf(v);
          } else if (MODE == 1){
            o0[rb + cols[j]] = f2bf(v);
          } else {
            of[rb + cols[j]] = gelu_f(v);
          }
          if (STATS && do_stats){
            colsum[j] += v;
            colsq[j]  = fmaf(v, v, colsq[j]);
          }
        }
      }
    }
  }

  if (STATS){
    #pragma unroll
    for (int j = 0; j < 4; ++j){
      colsum[j] += __shfl_xor(colsum[j], 16);
      colsum[j] += __shfl_xor(colsum[j], 32);
      colsq[j]  += __shfl_xor(colsq[j], 16);
      colsq[j]  += __shfl_xor(colsq[j], 32);
    }
    if ((lane >> 4) == 0 && do_stats){
      #pragma unroll
      for (int j = 0; j < 4; ++j)
        red[wr][wc * 64 + j * 16 + (lane & 15)] = make_float2(colsum[j], colsq[j]);
    }
    __syncthreads();
    if (tid < 128 && do_stats){
      float2 r0 = red[0][tid], r1 = red[1][tid];
      int gcol = n0 + tid - (MODE == 0 ? 512 : 0);
      partial[((size_t)b * 29 + mt) * 512 + gcol] = make_float2(r0.x + r1.x, r0.y + r1.y);
    }
  }
}

// --------------------------- IN stats stage-2 (29 partials) -----------------
__global__ void k_stats_p2b(const float2* __restrict__ partial, float2* __restrict__ stats){
  const int b = blockIdx.x;
  const int c = threadIdx.x;   // 512
  float s = 0.f, q = 0.f;
  for (int mt = 0; mt < 29; ++mt){
    float2 p = partial[((size_t)b * 29 + mt) * 512 + c];
    s += p.x; q += p.y;
  }
  float mean = s * (1.0f / (float)HW_);
  float var  = q * (1.0f / (float)HW_) - mean * mean;
  stats[(size_t)b * 512 + c] = make_float2(mean, rsqrtf(var + 1e-5f));
}

// --------------------------- attention prep ---------------------------------
__global__ void k_prep(const float* __restrict__ k_s, const float* __restrict__ v_s,
                       const float2* __restrict__ stats, const float* __restrict__ l_mask,
                       unsigned short* __restrict__ k2, unsigned short* __restrict__ v2,
                       float* __restrict__ e_s)
{
  const int b = blockIdx.x;
  const int tid = threadIdx.x;
  __shared__ float wred[4][NL_];

  float part[NL_];
  #pragma unroll
  for (int n = 0; n < NL_; ++n) part[n] = 0.f;
  #pragma unroll
  for (int half = 0; half < 2; ++half){
    int c = tid + half * 256;
    float2 st = stats[(size_t)b * 512 + c];
    float ms = st.x * st.y;
    const float* row = k_s + ((size_t)b * 512 + c) * NL_;
    #pragma unroll
    for (int n = 0; n < NL_; ++n) part[n] = fmaf(ms, row[n], part[n]);
  }
  #pragma unroll
  for (int n = 0; n < NL_; ++n){
    float v = part[n];
    v += __shfl_xor(v, 1);  v += __shfl_xor(v, 2);  v += __shfl_xor(v, 4);
    v += __shfl_xor(v, 8);  v += __shfl_xor(v, 16); v += __shfl_xor(v, 32);
    part[n] = v;
  }
  if ((tid & 63) == 0){
    #pragma unroll
    for (int n = 0; n < NL_; ++n) wred[tid >> 6][n] = part[n];
  }
  __syncthreads();
  if (tid < 32){
    float e;
    if (tid < NL_){
      float d = wred[0][tid] + wred[1][tid] + wred[2][tid] + wred[3][tid];
      e = -d - 10000.0f * (1.0f - l_mask[b * NL_ + tid]);
    } else {
      e = -1e30f;
    }
    e_s[b * 32 + tid] = e;
  }

  for (int i = tid; i < 16384; i += 256){
    int h = i >> 11, t = (i >> 10) & 1, s = (i >> 9) & 1;
    int l = (i >> 3) & 63, j = i & 7;
    int r = l & 15, g = l >> 4;
    int n = t * 16 + r;
    int c = h * 64 + s * 32 + g * 8 + j;
    unsigned short val = 0;
    if (n < NL_){
      float inv = stats[(size_t)b * 512 + c].y;
      val = f2bf(inv * k_s[((size_t)b * 512 + c) * NL_ + n]);
    }
    k2[(size_t)b * 16384 + i] = val;
  }
  for (int i = tid; i < 16384; i += 256){
    int h = i >> 11, ct = (i >> 9) & 3;
    int l = (i >> 3) & 63, j = i & 7;
    int r = l & 15, g = l >> 4;
    int n = g * 8 + j;
    int c = h * 64 + ct * 16 + r;
    unsigned short val = 0;
    if (n < NL_) val = f2bf(v_s[((size_t)b * 512 + c) * NL_ + n]);
    v2[(size_t)b * 16384 + i] = val;
  }
}

// --------------------------- attention (MFMA, swapped-QK) -------------------
__global__ __launch_bounds__(256) void k_attn2(unsigned short* __restrict__ qraw,
    const unsigned short* __restrict__ k2, const unsigned short* __restrict__ v2,
    const float* __restrict__ e_s)
{
  const int b = blockIdx.y;
  const int w = threadIdx.x >> 6;
  const int tile = blockIdx.x * 4 + w;
  __shared__ __align__(16) unsigned short p_sh[4][16 * 32];
  __shared__ __align__(16) unsigned short o_sh[4][16 * 72];
  if (tile >= 225) return;
  const int lane = threadIdx.x & 63;
  const int r = lane & 15, g = lane >> 4;
  const int row0 = tile * 16;

  float4v e0 = *(const float4v*)(e_s + b * 32 + g * 4);
  float4v e1 = *(const float4v*)(e_s + b * 32 + 16 + g * 4);

  bf16x8 qf[8][2];
  const unsigned short* qbase = qraw + ((size_t)(b * HW_ + row0 + r) * 512) + g * 8;
  #pragma unroll
  for (int h = 0; h < 8; ++h)
    #pragma unroll
    for (int s = 0; s < 2; ++s)
      qf[h][s] = *(const bf16x8*)(qbase + h * 64 + s * 32);

  const unsigned short* kb = k2 + (size_t)b * 16384 + lane * 8;
  const unsigned short* vb = v2 + (size_t)b * 16384 + lane * 8;
  unsigned short* psh = &p_sh[w][0];
  unsigned short* osh = &o_sh[w][0];

  for (int h = 0; h < 8; ++h){
    bf16x8 kf00 = *(const bf16x8*)(kb + (h * 4 + 0) * 512);
    bf16x8 kf01 = *(const bf16x8*)(kb + (h * 4 + 1) * 512);
    bf16x8 kf10 = *(const bf16x8*)(kb + (h * 4 + 2) * 512);
    bf16x8 kf11 = *(const bf16x8*)(kb + (h * 4 + 3) * 512);
    f32x4 c0 = (f32x4){0.f,0.f,0.f,0.f};
    f32x4 c1 = (f32x4){0.f,0.f,0.f,0.f};
    c0 = __builtin_amdgcn_mfma_f32_16x16x32_bf16(kf00, qf[h][0], c0, 0, 0, 0);
    c0 = __builtin_amdgcn_mfma_f32_16x16x32_bf16(kf01, qf[h][1], c0, 0, 0, 0);
    c1 = __builtin_amdgcn_mfma_f32_16x16x32_bf16(kf10, qf[h][0], c1, 0, 0, 0);
    c1 = __builtin_amdgcn_mfma_f32_16x16x32_bf16(kf11, qf[h][1], c1, 0, 0, 0);

    float l0[4], l1[4];
    #pragma unroll
    for (int i = 0; i < 4; ++i){ l0[i] = c0[i] + e0[i]; l1[i] = c1[i] + e1[i]; }
    float m = fmaxf(fmaxf(fmaxf(l0[0], l0[1]), fmaxf(l0[2], l0[3])),
                    fmaxf(fmaxf(l1[0], l1[1]), fmaxf(l1[2], l1[3])));
    m = fmaxf(m, __shfl_xor(m, 16));
    m = fmaxf(m, __shfl_xor(m, 32));
    float p0[4], p1[4];
    #pragma unroll
    for (int i = 0; i < 4; ++i){ p0[i] = __expf(l0[i] - m); p1[i] = __expf(l1[i] - m); }

    // pack UNNORMALIZED P to bf16; sum the ROUNDED values; scale PV out by 1/sum.
    uint2v pw0, pw1;
    pw0.x = pack2bf(p0[0], p0[1]); pw0.y = pack2bf(p0[2], p0[3]);
    pw1.x = pack2bf(p1[0], p1[1]); pw1.y = pack2bf(p1[2], p1[3]);
    float sum = bf2f((unsigned short)(pw0.x & 0xffff)) + bf2f((unsigned short)(pw0.x >> 16))
              + bf2f((unsigned short)(pw0.y & 0xffff)) + bf2f((unsigned short)(pw0.y >> 16))
              + bf2f((unsigned short)(pw1.x & 0xffff)) + bf2f((unsigned short)(pw1.x >> 16))
              + bf2f((unsigned short)(pw1.y & 0xffff)) + bf2f((unsigned short)(pw1.y >> 16));
    sum += __shfl_xor(sum, 16);
    sum += __shfl_xor(sum, 32);
    float inv = 1.0f / sum;

    *(uint2v*)(psh + r * 32 + 4 * g)      = pw0;
    *(uint2v*)(psh + r * 32 + 16 + 4 * g) = pw1;
    bf16x8 pfrag = *(const bf16x8*)(psh + r * 32 + g * 8);

    f32x4 dd[4];
    #pragma unroll
    for (int ct = 0; ct < 4; ++ct){
      bf16x8 vf = *(const bf16x8*)(vb + (h * 4 + ct) * 512);
      f32x4 z = (f32x4){0.f,0.f,0.f,0.f};
      dd[ct] = __builtin_amdgcn_mfma_f32_16x16x32_bf16(vf, pfrag, z, 0, 0, 0);
    }
    #pragma unroll
    for (int ct = 0; ct < 4; ++ct){
      uint2v ow;
      ow.x = pack2bf(dd[ct][0] * inv, dd[ct][1] * inv);
      ow.y = pack2bf(dd[ct][2] * inv, dd[ct][3] * inv);
      *(uint2v*)(osh + r * 72 + ct * 16 + 4 * g) = ow;
    }
    int frow = lane >> 2, fch = lane & 3;
    ushort8v t0 = *(const ushort8v*)(osh + frow * 72 + fch * 16);
    ushort8v t1 = *(const ushort8v*)(osh + frow * 72 + fch * 16 + 8);
    unsigned short* gdst = qraw + ((size_t)(b * HW_ + row0 + frow) * 512) + h * 64 + fch * 16;
    *(ushort8v*)(gdst)     = t0;
    *(ushort8v*)(gdst + 8) = t1;
  }
}

// --------------------------- h = vis * IN(yw) (in-place over yw) ------------
__global__ __launch_bounds__(256) void k_hmul(unsigned short* __restrict__ yw,
    const unsigned short* __restrict__ visb, const float2* __restrict__ stats)
{
  const int b = blockIdx.y, blk = blockIdx.x;
  const int w = threadIdx.x >> 6, lane = threadIdx.x & 63;
  const int c0 = lane * 8;
  float mean[8], inv[8];
  #pragma unroll
  for (int j = 0; j < 8; ++j){
    float2 st = stats[(size_t)b * 512 + c0 + j];
    mean[j] = st.x; inv[j] = st.y;
  }
  for (int it = 0; it < 30; ++it){
    int row = blk * 120 + it * 4 + w;
    size_t off = ((size_t)b * HW_ + row) * 512 + c0;
    ushort8v yv = *(const ushort8v*)(yw + off);
    ushort8v vv = *(const ushort8v*)(visb + off);
    ushort8v hv;
    #pragma unroll
    for (int j = 0; j < 8; ++j){
      float lang = (bf2f(yv[j]) - mean[j]) * inv[j];
      hv[j] = f2bf(bf2f(vv[j]) * lang);
    }
    *(ushort8v*)(yw + off) = hv;
  }
}

// ---------------------------------------------------------------------------
extern "C" void kernel_launch(void* const* d_in, const int* in_sizes, int n_in,
                              void* d_out, int out_size, void* d_ws, size_t ws_size,
                              hipStream_t stream)
{
  const float* x     = (const float*)d_in[0];
  const float* l     = (const float*)d_in[1];
  const float* lmask = (const float*)d_in[2];
  const float* Wvis  = (const float*)d_in[3];
  const float* bvis  = (const float*)d_in[4];
  const float* Wq    = (const float*)d_in[5];
  const float* bq    = (const float*)d_in[6];
  const float* Wk    = (const float*)d_in[7];
  const float* bk    = (const float*)d_in[8];
  const float* Wval  = (const float*)d_in[9];
  const float* bval  = (const float*)d_in[10];
  const float* Ww    = (const float*)d_in[11];
  const float* bw    = (const float*)d_in[12];
  const float* Wmm   = (const float*)d_in[13];
  const float* bmm   = (const float*)d_in[14];
  float* out = (float*)d_out;

  char* ws = (char*)d_ws;
  if (ws_size < 240517120ull) return;
  unsigned short* xb    = (unsigned short*)(ws + 0);
  unsigned short* visb  = (unsigned short*)(ws + 58982400);
  unsigned short* qraw  = (unsigned short*)(ws + 117964800);
  unsigned short* yw    = (unsigned short*)(ws + 176947200);
  unsigned short* wcat  = (unsigned short*)(ws + 235929600);
  unsigned short* wwb   = (unsigned short*)(ws + 236978176);
  unsigned short* wmmb  = (unsigned short*)(ws + 237502464);
  float*  k_s    = (float*)(ws + 238026752);
  float*  v_s    = (float*)(ws + 238682112);
  float2* stats_q= (float2*)(ws + 240386048);
  float2* stats_w= (float2*)(ws + 240451584);
  // attention fragment buffers overlap xb (dead after GEMM0):
  unsigned short* k2 = (unsigned short*)(ws + 0);          // 512 KB
  unsigned short* v2 = (unsigned short*)(ws + 524288);     // 512 KB
  float*          e_s = (float*)(ws + 1048576);            // 2 KB
  // stats partials live in regions dead at their producer's time:
  float2* partial_q = (float2*)(ws + 176947200);           // yw region (dead during gemm0)
  float2* partial_w = (float2*)(ws + 1052672);             // old-xb region (dead during gemm1)

  // 1) bf16 conversions
  k_cvt<<<2048, 256, 0, stream>>>(x, xb, (B_ * HW_ * D_) / 4);
  k_cvt<<<256, 256, 0, stream>>>(Wvis, wcat, (512 * 512) / 4);
  k_cvt<<<256, 256, 0, stream>>>(Wq, wcat + 262144, (512 * 512) / 4);
  k_cvt<<<256, 256, 0, stream>>>(Ww, wwb, (512 * 512) / 4);
  k_cvt<<<256, 256, 0, stream>>>(Wmm, wmmb, (512 * 512) / 4);

  // 2) K/V projections (mask + bias + 1/sqrt(KC) folded)
  k_kv<<<dim3(16, B_), 256, 0, stream>>>(l, lmask, Wk, bk, Wval, bval, k_s, v_s);

  // 3) dual GEMM: vis = gelu(x@Wvis^T+bvis), qraw = x@Wq^T+bq  (+ q-stats partials)
  k_gemm<0, 8, true><<<29 * 8 * B_, 256, 0, stream>>>(xb, wcat, bvis, bq, visb, qraw, nullptr, partial_q);

  // 4) IN stats for q (stage 2 only)
  k_stats_p2b<<<B_, 512, 0, stream>>>(partial_q, stats_q);

  // 4.5) build MFMA fragments for attention (overwrites dead xb region)
  k_prep<<<B_, 256, 0, stream>>>(k_s, v_s, stats_q, lmask, k2, v2, e_s);

  // 5) MFMA attention, in-place over qraw
  k_attn2<<<dim3(57, B_), 256, 0, stream>>>(qraw, k2, v2, e_s);

  // 6) yw = attn_out @ Ww^T + bw  (+ w-stats partials)
  k_gemm<1, 4, true><<<29 * 4 * B_, 256, 0, stream>>>(qraw, wwb, bw, nullptr, yw, nullptr, nullptr, partial_w);

  // 7) IN stats for yw (stage 2 only)
  k_stats_p2b<<<B_, 512, 0, stream>>>(partial_w, stats_w);

  // 8) h = vis * IN(yw)   (in-place over yw)
  k_hmul<<<dim3(30, B_), 256, 0, stream>>>(yw, visb, stats_w);

  // 9) out = gelu(h @ Wmm^T + bmm)  (f32)
  k_gemm<2, 4, false><<<29 * 4 * B_, 256, 0, stream>>>(yw, wmmb, bmm, nullptr, nullptr, nullptr, out, nullptr);
}

// Round 6
// 455.028 us; speedup vs baseline: 1.3920x; 1.0275x over previous
//
#include <hip/hip_runtime.h>

// ---------------------------------------------------------------------------
// PWAM fused pipeline, bf16 MFMA GEMMs + MFMA attention (swapped-QK, IN folded)
// R6: R5 + race fix in the pipelined GEMM K-loop: drain lgkmcnt(0) (+sched
//     fence) BEFORE the s_barrier so no wave crosses the barrier with
//     in-flight ds_reads of the buffer the next stage() will overwrite.
// B=16, HW=3600, D=KC=VC=512, LC=768, NL=20, H=8
// ---------------------------------------------------------------------------

#define B_   16
#define HW_  3600
#define D_   512
#define LC_  768
#define NL_  20

typedef __attribute__((ext_vector_type(8))) __bf16 bf16x8;
typedef __attribute__((ext_vector_type(4))) float f32x4;
typedef __attribute__((ext_vector_type(4))) float float4v;
typedef __attribute__((ext_vector_type(8))) unsigned short ushort8v;
typedef __attribute__((ext_vector_type(4))) unsigned short ushort4v;
typedef __attribute__((ext_vector_type(2))) unsigned int uint2v;

static __device__ __forceinline__ float bf2f(unsigned short u){
  unsigned int x = ((unsigned int)u) << 16; float f;
  __builtin_memcpy(&f, &x, 4); return f;
}
static __device__ __forceinline__ unsigned short f2bf(float f){
  unsigned int x; __builtin_memcpy(&x, &f, 4);
  x += 0x7fffu + ((x >> 16) & 1u);
  return (unsigned short)(x >> 16);
}
static __device__ __forceinline__ unsigned int pack2bf(float lo, float hi){
  return (unsigned int)f2bf(lo) | ((unsigned int)f2bf(hi) << 16);
}
// gelu(x) = 0.5x(1+erf(x/sqrt2)); erf via A&S 7.1.26 (|err|<=1.5e-7), hw exp.
static __device__ __forceinline__ float gelu_f(float x){
  float z  = x * 0.7071067811865476f;
  float az = fabsf(z);
  float t = 1.0f / fmaf(0.3275911f, az, 1.0f);
  float p = fmaf(1.061405429f, t, -1.453152027f);
  p = fmaf(p, t, 1.421413741f);
  p = fmaf(p, t, -0.284496736f);
  p = fmaf(p, t, 0.254829592f);
  p = p * t;
  float er = 1.0f - p * __expf(-az * az);
  er = copysignf(er, z);
  return 0.5f * x * (1.0f + er);
}

// --------------------------- f32 -> bf16 convert ---------------------------
__global__ void k_cvt(const float* __restrict__ src, unsigned short* __restrict__ dst, int n4){
  int i = blockIdx.x * 256 + threadIdx.x;
  int stride = gridDim.x * 256;
  for (; i < n4; i += stride){
    float4v v = ((const float4v*)src)[i];
    ushort4v u;
    u.x = f2bf(v.x); u.y = f2bf(v.y); u.z = f2bf(v.z); u.w = f2bf(v.w);
    ((ushort4v*)dst)[i] = u;
  }
}

// --------------------------- K/V projections (tiny) -------------------------
__global__ void k_kv(const float* __restrict__ l, const float* __restrict__ l_mask,
                     const float* __restrict__ Wk, const float* __restrict__ bk,
                     const float* __restrict__ Wval, const float* __restrict__ bval,
                     float* __restrict__ k_s, float* __restrict__ v_s){
  const int b = blockIdx.y;
  const int part = blockIdx.x;
  const bool isK = part < 8;
  const int c0 = (part & 7) * 64;
  const float* W  = isK ? Wk : Wval;
  const float* bi = isK ? bk : bval;
  float* outp = isK ? k_s : v_s;

  __shared__ float l_sh[LC_ * NL_];
  for (int i = threadIdx.x; i < LC_ * NL_; i += 256)
    l_sh[i] = l[(size_t)b * LC_ * NL_ + i];
  __syncthreads();

  const int tid = threadIdx.x;
  const int cl = tid >> 2;
  const int q  = tid & 3;
  const int c  = c0 + cl;
  const float* wrow = W + (size_t)c * LC_;
  float acc[5] = {0.f,0.f,0.f,0.f,0.f};
  for (int i = 0; i < LC_; ++i){
    float wv = wrow[i];
    const float* lr = l_sh + i * NL_ + q * 5;
    acc[0] = fmaf(wv, lr[0], acc[0]);
    acc[1] = fmaf(wv, lr[1], acc[1]);
    acc[2] = fmaf(wv, lr[2], acc[2]);
    acc[3] = fmaf(wv, lr[3], acc[3]);
    acc[4] = fmaf(wv, lr[4], acc[4]);
  }
  const float bb = bi[c];
  #pragma unroll
  for (int n5 = 0; n5 < 5; ++n5){
    int n = q * 5 + n5;
    float m = l_mask[b * NL_ + n];
    float val = (acc[n5] + bb) * m;
    if (isK) val *= 0.04419417382415922f;   // 1/sqrt(512) folded into K
    outp[((size_t)b * 512 + c) * NL_ + n] = val;
  }
}

// --------------------------- GEMM (bf16 MFMA, 128x128 tile) -----------------
// 3-buffer LDS, counted vmcnt(4), raw s_barrier, pre-barrier lgkm drain.
// XOR bank swizzle, involution key ((row>>1)&3) on BOTH stage-source & read.
// MODE 0: dual out (NT=8): n<512 -> o0=bf16(gelu(c+bias0)); else o1=bf16(c+bias1)
// MODE 1: o0 = bf16(c + bias0)
// MODE 2: of = gelu(c + bias0)   (f32)
template<int MODE, int NT, bool STATS>
__global__ __launch_bounds__(256, 3) void k_gemm(
    const unsigned short* __restrict__ A,
    const unsigned short* __restrict__ Bm,
    const float* __restrict__ bias0, const float* __restrict__ bias1,
    unsigned short* __restrict__ o0, unsigned short* __restrict__ o1,
    float* __restrict__ of, float2* __restrict__ partial)
{
  __shared__ __align__(16) unsigned short sA[3][128 * 32];
  __shared__ __align__(16) unsigned short sB[3][128 * 32];
  __shared__ float2 red[2][128];

  // XCD-bijective swizzle: d%8 -> XCD; contiguous g-range per XCD, n fastest.
  const int nwg = 29 * NT * B_;
  const int per = nwg >> 3;
  const int d = blockIdx.x;
  const int g = (d & 7) * per + (d >> 3);
  constexpr int NSH = (NT == 8) ? 3 : 2;
  const int nt = g & (NT - 1);
  const int rem = g >> NSH;
  const int mt = rem % 29;
  const int b  = rem / 29;

  const int m0 = mt * 128;
  const int n0 = nt * 128;
  const int tid = threadIdx.x;
  const int w = tid >> 6, lane = tid & 63;
  const int wr = w >> 1, wc = w & 1;
  const int mvalid = HW_ - m0;
  const unsigned short* Ab = A + (size_t)b * HW_ * 512;

  f32x4 acc[4][4];
  #pragma unroll
  for (int i = 0; i < 4; ++i)
    #pragma unroll
    for (int j = 0; j < 4; ++j)
      acc[i][j] = (f32x4){0.f, 0.f, 0.f, 0.f};

  // stage: 4 global_load_lds (16B) per thread; LDS dest linear, global source
  // pre-swizzled by the involution so swizzled reads return logical data.
  auto stage = [&](int kt, int buf){
    const int k0 = kt * 32;
    #pragma unroll
    for (int s = 0; s < 2; ++s){
      int chunk = s * 256 + tid;
      int row = chunk >> 2, part = chunk & 3;
      int psrc = part ^ ((row >> 1) & 3);
      int grow = row < mvalid ? row : (mvalid - 1);
      const unsigned short* gsrc = Ab + ((size_t)(m0 + grow) * 512 + k0 + psrc * 8);
      unsigned short* ldst = &sA[buf][(s * 256 + w * 64) * 8];
      __builtin_amdgcn_global_load_lds((const __attribute__((address_space(1))) void*)gsrc,
                                       (__attribute__((address_space(3))) void*)ldst, 16, 0, 0);
    }
    #pragma unroll
    for (int s = 0; s < 2; ++s){
      int chunk = s * 256 + tid;
      int row = chunk >> 2, part = chunk & 3;
      int psrc = part ^ ((row >> 1) & 3);
      const unsigned short* gsrc = Bm + ((size_t)(n0 + row) * 512 + k0 + psrc * 8);
      unsigned short* ldst = &sB[buf][(s * 256 + w * 64) * 8];
      __builtin_amdgcn_global_load_lds((const __attribute__((address_space(1))) void*)gsrc,
                                       (__attribute__((address_space(3))) void*)ldst, 16, 0, 0);
    }
  };

  auto compute = [&](int buf){
    const unsigned short* lA = &sA[buf][(wr * 64) * 32];
    const unsigned short* lB = &sB[buf][(wc * 64) * 32];
    const int r = lane & 15, kb = lane >> 4;
    const int kx = (kb ^ ((r >> 1) & 3)) * 8;   // swizzled 16B slot
    bf16x8 av[4], bv[4];
    #pragma unroll
    for (int i = 0; i < 4; ++i) av[i] = *(const bf16x8*)(lA + (i * 16 + r) * 32 + kx);
    #pragma unroll
    for (int j = 0; j < 4; ++j) bv[j] = *(const bf16x8*)(lB + (j * 16 + r) * 32 + kx);
    #pragma unroll
    for (int i = 0; i < 4; ++i)
      #pragma unroll
      for (int j = 0; j < 4; ++j)
        acc[i][j] = __builtin_amdgcn_mfma_f32_16x16x32_bf16(av[i], bv[j], acc[i][j], 0, 0, 0);
  };

  // prologue: 2 K-tiles in flight
  stage(0, 0);
  stage(1, 1);
  int cur = 0;
  #pragma unroll
  for (int t = 0; t < 16; ++t){
    // RACE FIX: hardware-drain this wave's LDS ops BEFORE the barrier, and
    // fence the scheduler so nothing from compute(t-1) sinks past it. After
    // this, no wave can cross the barrier with in-flight ds_reads of the
    // buffer that stage(t+2) (issued post-barrier by other waves) overwrites.
    asm volatile("s_waitcnt lgkmcnt(0)" ::: "memory");
    __builtin_amdgcn_sched_barrier(0);
    if (t < 15) asm volatile("s_waitcnt vmcnt(4)" ::: "memory");
    else        asm volatile("s_waitcnt vmcnt(0)" ::: "memory");
    __builtin_amdgcn_s_barrier();
    __builtin_amdgcn_sched_barrier(0);
    if (t < 14){
      int nb = cur + 2; if (nb >= 3) nb -= 3;
      stage(t + 2, nb);
    }
    compute(cur);
    if (++cur == 3) cur = 0;
  }

  // ---- epilogue ----
  int cols[4]; float bsv[4];
  #pragma unroll
  for (int j = 0; j < 4; ++j){
    int col = n0 + wc * 64 + j * 16 + (lane & 15);
    cols[j] = col;
    if (MODE == 0) bsv[j] = (col < 512) ? bias0[col] : bias1[col - 512];
    else           bsv[j] = bias0[col];
  }
  const bool do_stats = STATS && (MODE != 0 || n0 >= 512);
  float colsum[4] = {0.f,0.f,0.f,0.f}, colsq[4] = {0.f,0.f,0.f,0.f};

  #pragma unroll
  for (int i = 0; i < 4; ++i){
    int rowb = m0 + wr * 64 + i * 16 + (lane >> 4) * 4;
    #pragma unroll
    for (int rr = 0; rr < 4; ++rr){
      int row = rowb + rr;
      if (row < HW_){
        size_t rb = ((size_t)b * HW_ + row) * 512;
        #pragma unroll
        for (int j = 0; j < 4; ++j){
          float v = acc[i][j][rr] + bsv[j];
          if (MODE == 0){
            if (cols[j] < 512) o0[rb + cols[j]]       = f2bf(gelu_f(v));
            else               o1[rb + cols[j] - 512] = f2bf(v);
          } else if (MODE == 1){
            o0[rb + cols[j]] = f2bf(v);
          } else {
            of[rb + cols[j]] = gelu_f(v);
          }
          if (STATS && do_stats){
            colsum[j] += v;
            colsq[j]  = fmaf(v, v, colsq[j]);
          }
        }
      }
    }
  }

  if (STATS){
    #pragma unroll
    for (int j = 0; j < 4; ++j){
      colsum[j] += __shfl_xor(colsum[j], 16);
      colsum[j] += __shfl_xor(colsum[j], 32);
      colsq[j]  += __shfl_xor(colsq[j], 16);
      colsq[j]  += __shfl_xor(colsq[j], 32);
    }
    if ((lane >> 4) == 0 && do_stats){
      #pragma unroll
      for (int j = 0; j < 4; ++j)
        red[wr][wc * 64 + j * 16 + (lane & 15)] = make_float2(colsum[j], colsq[j]);
    }
    __syncthreads();
    if (tid < 128 && do_stats){
      float2 r0 = red[0][tid], r1 = red[1][tid];
      int gcol = n0 + tid - (MODE == 0 ? 512 : 0);
      partial[((size_t)b * 29 + mt) * 512 + gcol] = make_float2(r0.x + r1.x, r0.y + r1.y);
    }
  }
}

// --------------------------- IN stats stage-2 (29 partials) -----------------
__global__ void k_stats_p2b(const float2* __restrict__ partial, float2* __restrict__ stats){
  const int b = blockIdx.x;
  const int c = threadIdx.x;   // 512
  float s = 0.f, q = 0.f;
  for (int mt = 0; mt < 29; ++mt){
    float2 p = partial[((size_t)b * 29 + mt) * 512 + c];
    s += p.x; q += p.y;
  }
  float mean = s * (1.0f / (float)HW_);
  float var  = q * (1.0f / (float)HW_) - mean * mean;
  stats[(size_t)b * 512 + c] = make_float2(mean, rsqrtf(var + 1e-5f));
}

// --------------------------- attention prep ---------------------------------
__global__ void k_prep(const float* __restrict__ k_s, const float* __restrict__ v_s,
                       const float2* __restrict__ stats, const float* __restrict__ l_mask,
                       unsigned short* __restrict__ k2, unsigned short* __restrict__ v2,
                       float* __restrict__ e_s)
{
  const int b = blockIdx.x;
  const int tid = threadIdx.x;
  __shared__ float wred[4][NL_];

  float part[NL_];
  #pragma unroll
  for (int n = 0; n < NL_; ++n) part[n] = 0.f;
  #pragma unroll
  for (int half = 0; half < 2; ++half){
    int c = tid + half * 256;
    float2 st = stats[(size_t)b * 512 + c];
    float ms = st.x * st.y;
    const float* row = k_s + ((size_t)b * 512 + c) * NL_;
    #pragma unroll
    for (int n = 0; n < NL_; ++n) part[n] = fmaf(ms, row[n], part[n]);
  }
  #pragma unroll
  for (int n = 0; n < NL_; ++n){
    float v = part[n];
    v += __shfl_xor(v, 1);  v += __shfl_xor(v, 2);  v += __shfl_xor(v, 4);
    v += __shfl_xor(v, 8);  v += __shfl_xor(v, 16); v += __shfl_xor(v, 32);
    part[n] = v;
  }
  if ((tid & 63) == 0){
    #pragma unroll
    for (int n = 0; n < NL_; ++n) wred[tid >> 6][n] = part[n];
  }
  __syncthreads();
  if (tid < 32){
    float e;
    if (tid < NL_){
      float d = wred[0][tid] + wred[1][tid] + wred[2][tid] + wred[3][tid];
      e = -d - 10000.0f * (1.0f - l_mask[b * NL_ + tid]);
    } else {
      e = -1e30f;
    }
    e_s[b * 32 + tid] = e;
  }

  for (int i = tid; i < 16384; i += 256){
    int h = i >> 11, t = (i >> 10) & 1, s = (i >> 9) & 1;
    int l = (i >> 3) & 63, j = i & 7;
    int r = l & 15, g = l >> 4;
    int n = t * 16 + r;
    int c = h * 64 + s * 32 + g * 8 + j;
    unsigned short val = 0;
    if (n < NL_){
      float inv = stats[(size_t)b * 512 + c].y;
      val = f2bf(inv * k_s[((size_t)b * 512 + c) * NL_ + n]);
    }
    k2[(size_t)b * 16384 + i] = val;
  }
  for (int i = tid; i < 16384; i += 256){
    int h = i >> 11, ct = (i >> 9) & 3;
    int l = (i >> 3) & 63, j = i & 7;
    int r = l & 15, g = l >> 4;
    int n = g * 8 + j;
    int c = h * 64 + ct * 16 + r;
    unsigned short val = 0;
    if (n < NL_) val = f2bf(v_s[((size_t)b * 512 + c) * NL_ + n]);
    v2[(size_t)b * 16384 + i] = val;
  }
}

// --------------------------- attention (MFMA, swapped-QK) -------------------
__global__ __launch_bounds__(256) void k_attn2(unsigned short* __restrict__ qraw,
    const unsigned short* __restrict__ k2, const unsigned short* __restrict__ v2,
    const float* __restrict__ e_s)
{
  const int b = blockIdx.y;
  const int w = threadIdx.x >> 6;
  const int tile = blockIdx.x * 4 + w;
  __shared__ __align__(16) unsigned short p_sh[4][16 * 32];
  __shared__ __align__(16) unsigned short o_sh[4][16 * 72];
  if (tile >= 225) return;
  const int lane = threadIdx.x & 63;
  const int r = lane & 15, g = lane >> 4;
  const int row0 = tile * 16;

  float4v e0 = *(const float4v*)(e_s + b * 32 + g * 4);
  float4v e1 = *(const float4v*)(e_s + b * 32 + 16 + g * 4);

  bf16x8 qf[8][2];
  const unsigned short* qbase = qraw + ((size_t)(b * HW_ + row0 + r) * 512) + g * 8;
  #pragma unroll
  for (int h = 0; h < 8; ++h)
    #pragma unroll
    for (int s = 0; s < 2; ++s)
      qf[h][s] = *(const bf16x8*)(qbase + h * 64 + s * 32);

  const unsigned short* kb = k2 + (size_t)b * 16384 + lane * 8;
  const unsigned short* vb = v2 + (size_t)b * 16384 + lane * 8;
  unsigned short* psh = &p_sh[w][0];
  unsigned short* osh = &o_sh[w][0];

  for (int h = 0; h < 8; ++h){
    bf16x8 kf00 = *(const bf16x8*)(kb + (h * 4 + 0) * 512);
    bf16x8 kf01 = *(const bf16x8*)(kb + (h * 4 + 1) * 512);
    bf16x8 kf10 = *(const bf16x8*)(kb + (h * 4 + 2) * 512);
    bf16x8 kf11 = *(const bf16x8*)(kb + (h * 4 + 3) * 512);
    f32x4 c0 = (f32x4){0.f,0.f,0.f,0.f};
    f32x4 c1 = (f32x4){0.f,0.f,0.f,0.f};
    c0 = __builtin_amdgcn_mfma_f32_16x16x32_bf16(kf00, qf[h][0], c0, 0, 0, 0);
    c0 = __builtin_amdgcn_mfma_f32_16x16x32_bf16(kf01, qf[h][1], c0, 0, 0, 0);
    c1 = __builtin_amdgcn_mfma_f32_16x16x32_bf16(kf10, qf[h][0], c1, 0, 0, 0);
    c1 = __builtin_amdgcn_mfma_f32_16x16x32_bf16(kf11, qf[h][1], c1, 0, 0, 0);

    float l0[4], l1[4];
    #pragma unroll
    for (int i = 0; i < 4; ++i){ l0[i] = c0[i] + e0[i]; l1[i] = c1[i] + e1[i]; }
    float m = fmaxf(fmaxf(fmaxf(l0[0], l0[1]), fmaxf(l0[2], l0[3])),
                    fmaxf(fmaxf(l1[0], l1[1]), fmaxf(l1[2], l1[3])));
    m = fmaxf(m, __shfl_xor(m, 16));
    m = fmaxf(m, __shfl_xor(m, 32));
    float p0[4], p1[4];
    #pragma unroll
    for (int i = 0; i < 4; ++i){ p0[i] = __expf(l0[i] - m); p1[i] = __expf(l1[i] - m); }

    uint2v pw0, pw1;
    pw0.x = pack2bf(p0[0], p0[1]); pw0.y = pack2bf(p0[2], p0[3]);
    pw1.x = pack2bf(p1[0], p1[1]); pw1.y = pack2bf(p1[2], p1[3]);
    float sum = bf2f((unsigned short)(pw0.x & 0xffff)) + bf2f((unsigned short)(pw0.x >> 16))
              + bf2f((unsigned short)(pw0.y & 0xffff)) + bf2f((unsigned short)(pw0.y >> 16))
              + bf2f((unsigned short)(pw1.x & 0xffff)) + bf2f((unsigned short)(pw1.x >> 16))
              + bf2f((unsigned short)(pw1.y & 0xffff)) + bf2f((unsigned short)(pw1.y >> 16));
    sum += __shfl_xor(sum, 16);
    sum += __shfl_xor(sum, 32);
    float inv = 1.0f / sum;

    *(uint2v*)(psh + r * 32 + 4 * g)      = pw0;
    *(uint2v*)(psh + r * 32 + 16 + 4 * g) = pw1;
    bf16x8 pfrag = *(const bf16x8*)(psh + r * 32 + g * 8);

    f32x4 dd[4];
    #pragma unroll
    for (int ct = 0; ct < 4; ++ct){
      bf16x8 vf = *(const bf16x8*)(vb + (h * 4 + ct) * 512);
      f32x4 z = (f32x4){0.f,0.f,0.f,0.f};
      dd[ct] = __builtin_amdgcn_mfma_f32_16x16x32_bf16(vf, pfrag, z, 0, 0, 0);
    }
    #pragma unroll
    for (int ct = 0; ct < 4; ++ct){
      uint2v ow;
      ow.x = pack2bf(dd[ct][0] * inv, dd[ct][1] * inv);
      ow.y = pack2bf(dd[ct][2] * inv, dd[ct][3] * inv);
      *(uint2v*)(osh + r * 72 + ct * 16 + 4 * g) = ow;
    }
    int frow = lane >> 2, fch = lane & 3;
    ushort8v t0 = *(const ushort8v*)(osh + frow * 72 + fch * 16);
    ushort8v t1 = *(const ushort8v*)(osh + frow * 72 + fch * 16 + 8);
    unsigned short* gdst = qraw + ((size_t)(b * HW_ + row0 + frow) * 512) + h * 64 + fch * 16;
    *(ushort8v*)(gdst)     = t0;
    *(ushort8v*)(gdst + 8) = t1;
  }
}

// --------------------------- h = vis * IN(yw) (in-place over yw) ------------
__global__ __launch_bounds__(256) void k_hmul(unsigned short* __restrict__ yw,
    const unsigned short* __restrict__ visb, const float2* __restrict__ stats)
{
  const int b = blockIdx.y, blk = blockIdx.x;
  const int w = threadIdx.x >> 6, lane = threadIdx.x & 63;
  const int c0 = lane * 8;
  float mean[8], inv[8];
  #pragma unroll
  for (int j = 0; j < 8; ++j){
    float2 st = stats[(size_t)b * 512 + c0 + j];
    mean[j] = st.x; inv[j] = st.y;
  }
  for (int it = 0; it < 30; ++it){
    int row = blk * 120 + it * 4 + w;
    size_t off = ((size_t)b * HW_ + row) * 512 + c0;
    ushort8v yv = *(const ushort8v*)(yw + off);
    ushort8v vv = *(const ushort8v*)(visb + off);
    ushort8v hv;
    #pragma unroll
    for (int j = 0; j < 8; ++j){
      float lang = (bf2f(yv[j]) - mean[j]) * inv[j];
      hv[j] = f2bf(bf2f(vv[j]) * lang);
    }
    *(ushort8v*)(yw + off) = hv;
  }
}

// ---------------------------------------------------------------------------
extern "C" void kernel_launch(void* const* d_in, const int* in_sizes, int n_in,
                              void* d_out, int out_size, void* d_ws, size_t ws_size,
                              hipStream_t stream)
{
  const float* x     = (const float*)d_in[0];
  const float* l     = (const float*)d_in[1];
  const float* lmask = (const float*)d_in[2];
  const float* Wvis  = (const float*)d_in[3];
  const float* bvis  = (const float*)d_in[4];
  const float* Wq    = (const float*)d_in[5];
  const float* bq    = (const float*)d_in[6];
  const float* Wk    = (const float*)d_in[7];
  const float* bk    = (const float*)d_in[8];
  const float* Wval  = (const float*)d_in[9];
  const float* bval  = (const float*)d_in[10];
  const float* Ww    = (const float*)d_in[11];
  const float* bw    = (const float*)d_in[12];
  const float* Wmm   = (const float*)d_in[13];
  const float* bmm   = (const float*)d_in[14];
  float* out = (float*)d_out;

  char* ws = (char*)d_ws;
  if (ws_size < 240517120ull) return;
  unsigned short* xb    = (unsigned short*)(ws + 0);
  unsigned short* visb  = (unsigned short*)(ws + 58982400);
  unsigned short* qraw  = (unsigned short*)(ws + 117964800);
  unsigned short* yw    = (unsigned short*)(ws + 176947200);
  unsigned short* wcat  = (unsigned short*)(ws + 235929600);
  unsigned short* wwb   = (unsigned short*)(ws + 236978176);
  unsigned short* wmmb  = (unsigned short*)(ws + 237502464);
  float*  k_s    = (float*)(ws + 238026752);
  float*  v_s    = (float*)(ws + 238682112);
  float2* stats_q= (float2*)(ws + 240386048);
  float2* stats_w= (float2*)(ws + 240451584);
  // attention fragment buffers overlap xb (dead after GEMM0):
  unsigned short* k2 = (unsigned short*)(ws + 0);          // 512 KB
  unsigned short* v2 = (unsigned short*)(ws + 524288);     // 512 KB
  float*          e_s = (float*)(ws + 1048576);            // 2 KB
  // stats partials in regions dead at their producer's time:
  float2* partial_q = (float2*)(ws + 176947200);           // yw region (dead during gemm0)
  float2* partial_w = (float2*)(ws + 1052672);             // old-xb region (dead during gemm1)

  // 1) bf16 conversions
  k_cvt<<<2048, 256, 0, stream>>>(x, xb, (B_ * HW_ * D_) / 4);
  k_cvt<<<256, 256, 0, stream>>>(Wvis, wcat, (512 * 512) / 4);
  k_cvt<<<256, 256, 0, stream>>>(Wq, wcat + 262144, (512 * 512) / 4);
  k_cvt<<<256, 256, 0, stream>>>(Ww, wwb, (512 * 512) / 4);
  k_cvt<<<256, 256, 0, stream>>>(Wmm, wmmb, (512 * 512) / 4);

  // 2) K/V projections (mask + bias + 1/sqrt(KC) folded)
  k_kv<<<dim3(16, B_), 256, 0, stream>>>(l, lmask, Wk, bk, Wval, bval, k_s, v_s);

  // 3) dual GEMM: vis = gelu(x@Wvis^T+bvis), qraw = x@Wq^T+bq  (+ q-stats partials)
  k_gemm<0, 8, true><<<29 * 8 * B_, 256, 0, stream>>>(xb, wcat, bvis, bq, visb, qraw, nullptr, partial_q);

  // 4) IN stats for q (stage 2 only)
  k_stats_p2b<<<B_, 512, 0, stream>>>(partial_q, stats_q);

  // 4.5) build MFMA fragments for attention (overwrites dead xb region)
  k_prep<<<B_, 256, 0, stream>>>(k_s, v_s, stats_q, lmask, k2, v2, e_s);

  // 5) MFMA attention, in-place over qraw
  k_attn2<<<dim3(57, B_), 256, 0, stream>>>(qraw, k2, v2, e_s);

  // 6) yw = attn_out @ Ww^T + bw  (+ w-stats partials)
  k_gemm<1, 4, true><<<29 * 4 * B_, 256, 0, stream>>>(qraw, wwb, bw, nullptr, yw, nullptr, nullptr, partial_w);

  // 7) IN stats for yw (stage 2 only)
  k_stats_p2b<<<B_, 512, 0, stream>>>(partial_w, stats_w);

  // 8) h = vis * IN(yw)   (in-place over yw)
  k_hmul<<<dim3(30, B_), 256, 0, stream>>>(yw, visb, stats_w);

  // 9) out = gelu(h @ Wmm^T + bmm)  (f32)
  k_gemm<2, 4, false><<<29 * 4 * B_, 256, 0, stream>>>(yw, wmmb, bmm, nullptr, nullptr, nullptr, out, nullptr);
}